// Round 12
// baseline (685.429 us; speedup 1.0000x reference)
//
#include <hip/hip_runtime.h>
#include <hip/hip_fp16.h>

typedef _Float16 f16;
typedef _Float16 f16x8 __attribute__((ext_vector_type(8)));
typedef __fp16 fp16x2_raw __attribute__((ext_vector_type(2)));
typedef float f32x4 __attribute__((ext_vector_type(4)));

#define DD 512
#define BM 16     // entities per block (2 evo halves of 8)
#define WW 6
#define NH 8
#define EP 520    // padded LDS row stride (f16): rows offset +4 banks -> ~2-way conflicts

union F16x8 { f16x8 v; unsigned u[4]; uint2 u2[2]; };
union H2U { __half2 h; unsigned u; };
union U4H { uint4 q; __half2 h[4]; };

__device__ __forceinline__ unsigned pkrtz(float a, float b) {
  union { fp16x2_raw h; unsigned u; } c;
  c.h = __builtin_amdgcn_cvt_pkrtz(a, b);
  return c.u;
}
__device__ __forceinline__ unsigned short f2h(float x) {
  union { f16 h; unsigned short u; } c; c.h = (f16)x; return c.u;
}
#define SCHED_FENCE() __builtin_amdgcn_sched_barrier(0)

// ---- prep: gather Wq/Wv (512x512) into per-(head,ct,kst) A/B fragment-order, f16 ----
__global__ void k_prep_qv(const float* __restrict__ src, unsigned short* __restrict__ dst) {
  int i = blockIdx.x * 256 + threadIdx.x;   // 65536 threads, 4 j each
  int j0 = (i & 1) * 4;
  int lane = (i >> 1) & 63;
  int kst = (i >> 7) & 15;
  int ct = (i >> 11) & 3;
  int wv = (i >> 13) & 7;
  int col = wv * 64 + ct * 16 + (lane & 15);
  int row = kst * 32 + (lane >> 4) * 8 + j0;
  ushort4 o;
  o.x = f2h(src[(size_t)(row + 0) * DD + col]);
  o.y = f2h(src[(size_t)(row + 1) * DD + col]);
  o.z = f2h(src[(size_t)(row + 2) * DD + col]);
  o.w = f2h(src[(size_t)(row + 3) * DD + col]);
  *(ushort4*)&dst[(size_t)(((wv * 4 + ct) * 16 + kst) * 64 + lane) * 8 + j0] = o;
}

// ---- prep: gather Wk into qk-A-frag order (sigma slot permutation baked in) ----
__global__ void k_prep_wk(const float* __restrict__ src, unsigned short* __restrict__ dst) {
  int i = blockIdx.x * 256 + threadIdx.x;   // 65536 threads
  int j0 = (i & 1) * 4;
  int lane = (i >> 1) & 63;
  int ab = (i >> 7) & 1;
  int kst = (i >> 8) & 1;
  int ch = (i >> 9) & 15;
  int wv = (i >> 13) & 7;
  int row = ch * 32 + ab * 16 + (lane & 15);
  int cb = wv * 64 + kst * 32 + (j0 ? 16 : 0) + ((lane >> 4) & 3) * 4;
  float4 v = *(const float4*)&src[(size_t)row * DD + cb];
  ushort4 o; o.x = f2h(v.x); o.y = f2h(v.y); o.z = f2h(v.z); o.w = f2h(v.w);
  *(ushort4*)&dst[(size_t)((((wv * 16 + ch) * 2 + kst) * 2 + ab) * 64 + lane) * 8 + j0] = o;
}

// ---- prep: gather W1 (512x256) ----
__global__ void k_prep_w1(const float* __restrict__ src, unsigned short* __restrict__ dst) {
  int i = blockIdx.x * 256 + threadIdx.x;   // 32768 threads
  int j0 = (i & 1) * 4;
  int lane = (i >> 1) & 63;
  int kst = (i >> 7) & 15;
  int ct = (i >> 11) & 1;
  int wv = (i >> 12) & 7;
  int col = wv * 32 + ct * 16 + (lane & 15);
  int row = kst * 32 + (lane >> 4) * 8 + j0;
  ushort4 o;
  o.x = f2h(src[(size_t)(row + 0) * 256 + col]);
  o.y = f2h(src[(size_t)(row + 1) * 256 + col]);
  o.z = f2h(src[(size_t)(row + 2) * 256 + col]);
  o.w = f2h(src[(size_t)(row + 3) * 256 + col]);
  *(ushort4*)&dst[(size_t)(((wv * 2 + ct) * 16 + kst) * 64 + lane) * 8 + j0] = o;
}

// ---------- main: 16 entities/block, 8 waves = 8 heads, evo in 2 halves, f16 ----------
// launch_bounds(512,3): min 3 BLOCKS/CU (CUDA min-blocks semantics, r3) -> ~84 arch-VGPR cap.
// LDS 70.6KB still limits residency to 2 blocks/CU (16 waves, occ ~44%) -- the extra ~20 regs
// vs r11's 64-cap are spent on depth-1 weight-fragment PREFETCH in P1/score/agg loops to
// double global-load MLP (r11 diagnosis: latency-bound, ~4 loads in flight per chunk).
__global__ __launch_bounds__(512, 3) void trust_main(
    const float* __restrict__ h_i, const float* __restrict__ evo,
    const float* __restrict__ var_i, const float* __restrict__ var_j,
    const float* __restrict__ bq, const float* __restrict__ bk, const float* __restrict__ bv,
    const float* __restrict__ ld, const float* __restrict__ b1,
    const float* __restrict__ W2, const float* __restrict__ b2,
    const unsigned short* __restrict__ wqA, const unsigned short* __restrict__ wkA,
    const unsigned short* __restrict__ wvA, const unsigned short* __restrict__ w1A,
    float* __restrict__ out) {
  __shared__ unsigned short evo_s[48 * EP];   // 49920 B, one half (8 ents x 6 w)
  __shared__ unsigned short qh_s[16 * EP];    // 16640 B, h -> pooled (16 rows)
  __shared__ float score_s[NH * BM * WW];     // 3072 B
  __shared__ float logit_s[BM * NH];          // 512 B
  __shared__ float conf_s[BM];                // 64 B
  // total 70208 B -> 2 blocks/CU

  const int t = threadIdx.x;
  const int wv = t >> 6;       // wave == head
  const int l = t & 63;
  const int l16 = l & 15;
  const int lq = l >> 4;
  const int e0 = blockIdx.x * BM;

  // decay bias
  float biasw[WW];
  {
    float rd = expf(ld[0]);
    float dsum = 0.f;
    #pragma unroll
    for (int w6 = 0; w6 < WW; ++w6) { biasw[w6] = expf(rd * (float)w6); dsum += biasw[w6]; }
    float dinv = 1.f / dsum;
    #pragma unroll
    for (int w6 = 0; w6 < WW; ++w6) biasw[w6] *= dinv;
  }

  const float4* ev4 = (const float4*)evo + (size_t)e0 * (WW * DD / 4);

  // ---- P0: stage evo half0 (ents 0-7) + h (16 rows) to LDS f16; conf ----
  {
    #pragma unroll 4
    for (int i = 0; i < 12; ++i) {
      int idx = i * 512 + t;
      int row = idx >> 7, c4 = idx & 127;
      float4 v = ev4[idx];
      uint2 o; o.x = pkrtz(v.x, v.y); o.y = pkrtz(v.z, v.w);
      *(uint2*)&evo_s[row * EP + c4 * 4] = o;
    }
    const float4* h4 = (const float4*)h_i + (size_t)e0 * (DD / 4);
    #pragma unroll
    for (int i = 0; i < 4; ++i) {
      int idx = i * 512 + t;
      int row = idx >> 7, c4 = idx & 127;
      float4 v = h4[idx];
      uint2 o; o.x = pkrtz(v.x, v.y); o.y = pkrtz(v.z, v.w);
      *(uint2*)&qh_s[row * EP + c4 * 4] = o;
    }
    int ce = t >> 5, cs = t & 31;
    const float4* vi4 = (const float4*)var_i + (size_t)(e0 + ce) * (DD / 4);
    const float4* vj4 = (const float4*)var_j + (size_t)(e0 + ce) * (DD / 4);
    float si = 0.f, sj = 0.f;
    #pragma unroll
    for (int i = 0; i < 4; ++i) {
      float4 a = vi4[i * 32 + cs]; si += a.x + a.y + a.z + a.w;
      float4 b = vj4[i * 32 + cs]; sj += b.x + b.y + b.z + b.w;
    }
    #pragma unroll
    for (int m = 1; m <= 16; m <<= 1) { si += __shfl_xor(si, m); sj += __shfl_xor(sj, m); }
    if (cs == 0) {
      float ci = 1.f / (1.f + fmaxf(sqrtf(si * (1.f / DD)), 1e-6f));
      float cj = 1.f / (1.f + fmaxf(sqrtf(sj * (1.f / DD)), 1e-6f));
      conf_s[ce] = fmaxf(0.5f * (logf(ci) + logf(cj)), -5.0f);
    }
  }
  __syncthreads();   // B1
  SCHED_FENCE();

  // ---- P1: Q^T per head; Q stays in regs. Depth-1 prefetch on wqA stream ----
  F16x8 qfr[2];      // qk B-frags, sigma slot order
  float qb;          // Q[e].bk at lane l16=e
  {
    f32x4 qacc[4] = {};
    const unsigned short* wqp = wqA + (size_t)wv * 4 * 16 * 512 + l * 8;
    F16x8 cq0, cq1, cq2, cq3, nq0, nq1, nq2, nq3;
    cq0.v = *reinterpret_cast<const f16x8*>(&wqp[(0 * 16 + 0) * 512]);
    cq1.v = *reinterpret_cast<const f16x8*>(&wqp[(1 * 16 + 0) * 512]);
    cq2.v = *reinterpret_cast<const f16x8*>(&wqp[(2 * 16 + 0) * 512]);
    cq3.v = *reinterpret_cast<const f16x8*>(&wqp[(3 * 16 + 0) * 512]);
    #pragma unroll 1
    for (int kst = 0; kst < 16; ++kst) {
      if (kst < 15) {
        nq0.v = *reinterpret_cast<const f16x8*>(&wqp[(0 * 16 + kst + 1) * 512]);
        nq1.v = *reinterpret_cast<const f16x8*>(&wqp[(1 * 16 + kst + 1) * 512]);
        nq2.v = *reinterpret_cast<const f16x8*>(&wqp[(2 * 16 + kst + 1) * 512]);
        nq3.v = *reinterpret_cast<const f16x8*>(&wqp[(3 * 16 + kst + 1) * 512]);
      }
      SCHED_FENCE();
      f16x8 hb = *reinterpret_cast<const f16x8*>(&qh_s[l16 * EP + kst * 32 + lq * 8]);
      qacc[0] = __builtin_amdgcn_mfma_f32_16x16x32_f16(cq0.v, hb, qacc[0], 0, 0, 0);
      qacc[1] = __builtin_amdgcn_mfma_f32_16x16x32_f16(cq1.v, hb, qacc[1], 0, 0, 0);
      qacc[2] = __builtin_amdgcn_mfma_f32_16x16x32_f16(cq2.v, hb, qacc[2], 0, 0, 0);
      qacc[3] = __builtin_amdgcn_mfma_f32_16x16x32_f16(cq3.v, hb, qacc[3], 0, 0, 0);
      cq0 = nq0; cq1 = nq1; cq2 = nq2; cq3 = nq3;
    }
    qb = 0.f;
    #pragma unroll
    for (int ct = 0; ct < 4; ++ct) {
      float4 bq4 = *(const float4*)&bq[wv * 64 + ct * 16 + lq * 4];
      float4 bk4 = *(const float4*)&bk[wv * 64 + ct * 16 + lq * 4];
      float q0 = qacc[ct][0] + bq4.x, q1 = qacc[ct][1] + bq4.y;
      float q2 = qacc[ct][2] + bq4.z, q3 = qacc[ct][3] + bq4.w;
      qb += q0 * bk4.x + q1 * bk4.y + q2 * bk4.z + q3 * bk4.w;
      qfr[ct >> 1].u[(ct & 1) * 2]     = pkrtz(q0, q1);
      qfr[ct >> 1].u[(ct & 1) * 2 + 1] = pkrtz(q2, q3);
    }
    qb += __shfl_xor(qb, 16);
    qb += __shfl_xor(qb, 32);   // lane l16=e holds qb[e]
  }
  SCHED_FENCE();

  f32x4 pacc[4] = {};   // pooled accumulator (spans both halves)
  const unsigned short* wkp = wkA + (size_t)wv * 16 * 2 * 2 * 512 + l * 8;
  const unsigned short* wvp = wvA + (size_t)wv * 4 * 16 * 512 + l * 8;

  #pragma unroll
  for (int H = 0; H < 2; ++H) {
    if (H == 1) {
      __syncthreads();   // B2: all waves done reading evo half0
      const float4* ev4b = ev4 + 6144;
      #pragma unroll 4
      for (int i = 0; i < 12; ++i) {
        int idx = i * 512 + t;
        int row = idx >> 7, c4 = idx & 127;
        float4 v = ev4b[idx];
        uint2 o; o.x = pkrtz(v.x, v.y); o.y = pkrtz(v.z, v.w);
        *(uint2*)&evo_s[row * EP + c4 * 4] = o;
      }
      __syncthreads();   // B3
    }

    // ---- score: Qk chunk -> af -> 3 evo MFMAs; depth-1 prefetch on wkA stream ----
    f32x4 sacc0 = {}, sacc1 = {}, sacc2 = {};
    {
      F16x8 c00, c01, c10, c11, n00, n01, n10, n11;
      c00.v = *reinterpret_cast<const f16x8*>(&wkp[0 * 512]);
      c01.v = *reinterpret_cast<const f16x8*>(&wkp[1 * 512]);
      c10.v = *reinterpret_cast<const f16x8*>(&wkp[2 * 512]);
      c11.v = *reinterpret_cast<const f16x8*>(&wkp[3 * 512]);
      #pragma unroll 1
      for (int ch = 0; ch < 16; ++ch) {
        if (ch < 15) {
          n00.v = *reinterpret_cast<const f16x8*>(&wkp[((ch + 1) * 4 + 0) * 512]);
          n01.v = *reinterpret_cast<const f16x8*>(&wkp[((ch + 1) * 4 + 1) * 512]);
          n10.v = *reinterpret_cast<const f16x8*>(&wkp[((ch + 1) * 4 + 2) * 512]);
          n11.v = *reinterpret_cast<const f16x8*>(&wkp[((ch + 1) * 4 + 3) * 512]);
        }
        SCHED_FENCE();
        f32x4 qk0 = {}, qk1 = {};
        qk0 = __builtin_amdgcn_mfma_f32_16x16x32_f16(c00.v, qfr[0].v, qk0, 0, 0, 0);
        qk1 = __builtin_amdgcn_mfma_f32_16x16x32_f16(c01.v, qfr[0].v, qk1, 0, 0, 0);
        qk0 = __builtin_amdgcn_mfma_f32_16x16x32_f16(c10.v, qfr[1].v, qk0, 0, 0, 0);
        qk1 = __builtin_amdgcn_mfma_f32_16x16x32_f16(c11.v, qfr[1].v, qk1, 0, 0, 0);
        F16x8 af;
        af.u[0] = pkrtz(qk0[0], qk0[1]); af.u[1] = pkrtz(qk0[2], qk0[3]);
        af.u[2] = pkrtz(qk1[0], qk1[1]); af.u[3] = pkrtz(qk1[2], qk1[3]);
        int cb = ch * 32 + lq * 4;
        {
          F16x8 b; b.u2[0] = *(const uint2*)&evo_s[l16 * EP + cb];
          b.u2[1] = *(const uint2*)&evo_s[l16 * EP + cb + 16];
          sacc0 = __builtin_amdgcn_mfma_f32_16x16x32_f16(af.v, b.v, sacc0, 0, 0, 0);
        }
        {
          F16x8 b; b.u2[0] = *(const uint2*)&evo_s[(16 + l16) * EP + cb];
          b.u2[1] = *(const uint2*)&evo_s[(16 + l16) * EP + cb + 16];
          sacc1 = __builtin_amdgcn_mfma_f32_16x16x32_f16(af.v, b.v, sacc1, 0, 0, 0);
        }
        {
          F16x8 b; b.u2[0] = *(const uint2*)&evo_s[(32 + l16) * EP + cb];
          b.u2[1] = *(const uint2*)&evo_s[(32 + l16) * EP + cb + 16];
          sacc2 = __builtin_amdgcn_mfma_f32_16x16x32_f16(af.v, b.v, sacc2, 0, 0, 0);
        }
        c00 = n00; c01 = n01; c10 = n10; c11 = n11;
      }
    }
    SCHED_FENCE();

    // extract S[e][w]: D rows = entities, cols l16 -> half-local evo row L = 6*eL + w
    #pragma unroll
    for (int r = 0; r < 4; ++r) {
      int e = lq * 4 + r, eL = e - 8 * H;
      { int w = l16 - 6 * eL;      if (w >= 0 && w < WW) score_s[wv * 96 + e * 6 + w] = sacc0[r]; }
      { int w = 16 + l16 - 6 * eL; if (w >= 0 && w < WW) score_s[wv * 96 + e * 6 + w] = sacc1[r]; }
      { int w = 32 + l16 - 6 * eL; if (w >= 0 && w < WW) score_s[wv * 96 + e * 6 + w] = sacc2[r]; }
    }
    // softmax for this half's entities (attn written back by l16==0 lanes)
    #pragma unroll
    for (int r = 0; r < 4; ++r) {
      int e = lq * 4 + r, eL = e - 8 * H;
      if (eL >= 0 && eL < 8) {
        float qbv = __shfl(qb, e);
        float sc[WW]; float mx = -1e30f;
        #pragma unroll
        for (int w6 = 0; w6 < WW; ++w6) {
          sc[w6] = 0.125f * (score_s[wv * 96 + e * 6 + w6] + qbv) + biasw[w6];
          mx = fmaxf(mx, sc[w6]);
        }
        float ssum = 0.f;
        #pragma unroll
        for (int w6 = 0; w6 < WW; ++w6) { sc[w6] = expf(sc[w6] - mx); ssum += sc[w6]; }
        float sinv = 1.f / ssum;
        if (l16 == 0) {
          #pragma unroll
          for (int w6 = 0; w6 < WW; ++w6) score_s[wv * 96 + e * 6 + w6] = sc[w6] * sinv;
        }
      }
    }
    SCHED_FENCE();

    // ---- agg via hfma2 (lane = entity l16); depth-1 prefetch on wvA stream ----
    {
      __half2 aw2[WW];
      bool inh = ((l16 >> 3) == H);
      #pragma unroll
      for (int w6 = 0; w6 < WW; ++w6) {
        float v = score_s[wv * 96 + l16 * 6 + w6];
        v = inh ? v : 0.f;
        H2U a; a.u = pkrtz(v, v); aw2[w6] = a.h;
      }
      const int arow = (l16 & 7) * 6;
      F16x8 cv0, cv1, cv2, cv3, nv0, nv1, nv2, nv3;
      cv0.v = *reinterpret_cast<const f16x8*>(&wvp[(0 * 16 + 0) * 512]);
      cv1.v = *reinterpret_cast<const f16x8*>(&wvp[(1 * 16 + 0) * 512]);
      cv2.v = *reinterpret_cast<const f16x8*>(&wvp[(2 * 16 + 0) * 512]);
      cv3.v = *reinterpret_cast<const f16x8*>(&wvp[(3 * 16 + 0) * 512]);
      #pragma unroll 1
      for (int ch = 0; ch < 16; ++ch) {
        if (ch < 15) {
          nv0.v = *reinterpret_cast<const f16x8*>(&wvp[(0 * 16 + ch + 1) * 512]);
          nv1.v = *reinterpret_cast<const f16x8*>(&wvp[(1 * 16 + ch + 1) * 512]);
          nv2.v = *reinterpret_cast<const f16x8*>(&wvp[(2 * 16 + ch + 1) * 512]);
          nv3.v = *reinterpret_cast<const f16x8*>(&wvp[(3 * 16 + ch + 1) * 512]);
        }
        SCHED_FENCE();
        H2U z; z.u = 0;
        __half2 ac0 = z.h, ac1 = z.h, ac2 = z.h, ac3 = z.h;
        #pragma unroll
        for (int w6 = 0; w6 < WW; ++w6) {
          U4H vv; vv.q = *(const uint4*)&evo_s[(arow + w6) * EP + ch * 32 + lq * 8];
          ac0 = __hfma2(vv.h[0], aw2[w6], ac0);
          ac1 = __hfma2(vv.h[1], aw2[w6], ac1);
          ac2 = __hfma2(vv.h[2], aw2[w6], ac2);
          ac3 = __hfma2(vv.h[3], aw2[w6], ac3);
        }
        F16x8 af;
        { H2U c; c.h = ac0; af.u[0] = c.u; c.h = ac1; af.u[1] = c.u;
          c.h = ac2; af.u[2] = c.u; c.h = ac3; af.u[3] = c.u; }
        pacc[0] = __builtin_amdgcn_mfma_f32_16x16x32_f16(af.v, cv0.v, pacc[0], 0, 0, 0);
        pacc[1] = __builtin_amdgcn_mfma_f32_16x16x32_f16(af.v, cv1.v, pacc[1], 0, 0, 0);
        pacc[2] = __builtin_amdgcn_mfma_f32_16x16x32_f16(af.v, cv2.v, pacc[2], 0, 0, 0);
        pacc[3] = __builtin_amdgcn_mfma_f32_16x16x32_f16(af.v, cv3.v, pacc[3], 0, 0, 0);
        cv0 = nv0; cv1 = nv1; cv2 = nv2; cv3 = nv3;
      }
    }
  }

  // pooled -> qh_s (f16)
  #pragma unroll
  for (int ct = 0; ct < 4; ++ct) {
    int col = wv * 64 + ct * 16 + l16;
    float bvv = bv[col];
    #pragma unroll
    for (int r = 0; r < 4; ++r)
      qh_s[(lq * 4 + r) * EP + col] = f2h(pacc[ct][r] + bvv);
  }
  __syncthreads();   // B4

  // ---- P6: hmid = gelu(pooled @ W1 + b1); logit partials ----
  {
    f32x4 hacc[2] = {};
    const unsigned short* w1p = w1A + (size_t)wv * 2 * 16 * 512 + l * 8;
    #pragma unroll 2
    for (int kst = 0; kst < 16; ++kst) {
      f16x8 a = *reinterpret_cast<const f16x8*>(&qh_s[l16 * EP + kst * 32 + lq * 8]);
      #pragma unroll
      for (int ct = 0; ct < 2; ++ct) {
        f16x8 b = *reinterpret_cast<const f16x8*>(&w1p[(ct * 16 + kst) * 512]);
        hacc[ct] = __builtin_amdgcn_mfma_f32_16x16x32_f16(a, b, hacc[ct], 0, 0, 0);
      }
    }
    float lg[4] = {0.f, 0.f, 0.f, 0.f};
    #pragma unroll
    for (int ct = 0; ct < 2; ++ct) {
      int m = wv * 32 + ct * 16 + l16;
      float b1v = b1[m], w2v = W2[m];
      #pragma unroll
      for (int r = 0; r < 4; ++r) {
        float x = hacc[ct][r] + b1v;
        float g = 0.5f * x * (1.f + erff(x * 0.70710678118f));
        lg[r] += g * w2v;
      }
    }
    #pragma unroll
    for (int r = 0; r < 4; ++r) {
      #pragma unroll
      for (int m = 1; m <= 8; m <<= 1) lg[r] += __shfl_xor(lg[r], m);
    }
    if (l16 == 0) {
      #pragma unroll
      for (int r = 0; r < 4; ++r) logit_s[(lq * 4 + r) * NH + wv] = lg[r];
    }
  }
  __syncthreads();   // B5

  // ---- P7: combine + sigmoid ----
  if (t < BM) {
    float s = 0.f;
    #pragma unroll
    for (int w8 = 0; w8 < NH; ++w8) s += logit_s[t * NH + w8];
    s += b2[0] + conf_s[t];
    out[e0 + t] = 1.f / (1.f + expf(-s));
  }
}

extern "C" void kernel_launch(void* const* d_in, const int* in_sizes, int n_in,
                              void* d_out, int out_size, void* d_ws, size_t ws_size,
                              hipStream_t stream) {
  (void)in_sizes; (void)n_in; (void)out_size; (void)ws_size;
  const float* h_i = (const float*)d_in[0];
  const float* evo = (const float*)d_in[1];
  const float* vi  = (const float*)d_in[2];
  const float* vj  = (const float*)d_in[3];
  const float* Wq  = (const float*)d_in[4];
  const float* bq  = (const float*)d_in[5];
  const float* Wk  = (const float*)d_in[6];
  const float* bk  = (const float*)d_in[7];
  const float* Wv  = (const float*)d_in[8];
  const float* bv  = (const float*)d_in[9];
  const float* ld  = (const float*)d_in[10];
  const float* W1  = (const float*)d_in[11];
  const float* b1  = (const float*)d_in[12];
  const float* W2  = (const float*)d_in[13];
  const float* b2  = (const float*)d_in[14];
  float* out = (float*)d_out;

  unsigned short* ws  = (unsigned short*)d_ws;
  unsigned short* wqA = ws;            // 512KB f16, Wq fragment-order
  unsigned short* wkA = ws + 262144;   // 512KB f16, Wk qk-A-frag order
  unsigned short* wvA = ws + 524288;   // 512KB f16, Wv B-frag order
  unsigned short* w1A = ws + 786432;   // 256KB f16, W1 B-frag order

  k_prep_qv<<<256, 256, 0, stream>>>(Wq, wqA);
  k_prep_wk<<<256, 256, 0, stream>>>(Wk, wkA);
  k_prep_qv<<<256, 256, 0, stream>>>(Wv, wvA);
  k_prep_w1<<<128, 256, 0, stream>>>(W1, w1A);
  trust_main<<<3125, 512, 0, stream>>>(h_i, evo, vi, vj, bq, bk, bv, ld, b1, W2, b2,
                                       wqA, wkA, wvA, w1A, out);
}

// Round 13
// 497.510 us; speedup vs baseline: 1.3777x; 1.3777x over previous
//
#include <hip/hip_runtime.h>
#include <hip/hip_fp16.h>

typedef _Float16 f16;
typedef _Float16 f16x8 __attribute__((ext_vector_type(8)));
typedef __fp16 fp16x2_raw __attribute__((ext_vector_type(2)));
typedef float f32x4 __attribute__((ext_vector_type(4)));

#define DD 512
#define BM 16     // entities per block (2 evo halves of 8)
#define WW 6
#define NH 8
#define EP 520    // padded LDS row stride (f16): rows offset +4 banks -> ~2-way conflicts

union F16x8 { f16x8 v; unsigned u[4]; uint2 u2[2]; };
union H2U { __half2 h; unsigned u; };
union U4H { uint4 q; __half2 h[4]; };

__device__ __forceinline__ unsigned pkrtz(float a, float b) {
  union { fp16x2_raw h; unsigned u; } c;
  c.h = __builtin_amdgcn_cvt_pkrtz(a, b);
  return c.u;
}
__device__ __forceinline__ unsigned short f2h(float x) {
  union { f16 h; unsigned short u; } c; c.h = (f16)x; return c.u;
}
#define SCHED_FENCE() __builtin_amdgcn_sched_barrier(0)

// ---- prep: gather Wq/Wv (512x512) into per-(head,ct,kst) A/B fragment-order, f16 ----
__global__ void k_prep_qv(const float* __restrict__ src, unsigned short* __restrict__ dst) {
  int i = blockIdx.x * 256 + threadIdx.x;   // 65536 threads, 4 j each
  int j0 = (i & 1) * 4;
  int lane = (i >> 1) & 63;
  int kst = (i >> 7) & 15;
  int ct = (i >> 11) & 3;
  int wv = (i >> 13) & 7;
  int col = wv * 64 + ct * 16 + (lane & 15);
  int row = kst * 32 + (lane >> 4) * 8 + j0;
  ushort4 o;
  o.x = f2h(src[(size_t)(row + 0) * DD + col]);
  o.y = f2h(src[(size_t)(row + 1) * DD + col]);
  o.z = f2h(src[(size_t)(row + 2) * DD + col]);
  o.w = f2h(src[(size_t)(row + 3) * DD + col]);
  *(ushort4*)&dst[(size_t)(((wv * 4 + ct) * 16 + kst) * 64 + lane) * 8 + j0] = o;
}

// ---- prep: gather Wk into qk-A-frag order (sigma slot permutation baked in) ----
__global__ void k_prep_wk(const float* __restrict__ src, unsigned short* __restrict__ dst) {
  int i = blockIdx.x * 256 + threadIdx.x;   // 65536 threads
  int j0 = (i & 1) * 4;
  int lane = (i >> 1) & 63;
  int ab = (i >> 7) & 1;
  int kst = (i >> 8) & 1;
  int ch = (i >> 9) & 15;
  int wv = (i >> 13) & 7;
  int row = ch * 32 + ab * 16 + (lane & 15);
  int cb = wv * 64 + kst * 32 + (j0 ? 16 : 0) + ((lane >> 4) & 3) * 4;
  float4 v = *(const float4*)&src[(size_t)row * DD + cb];
  ushort4 o; o.x = f2h(v.x); o.y = f2h(v.y); o.z = f2h(v.z); o.w = f2h(v.w);
  *(ushort4*)&dst[(size_t)((((wv * 16 + ch) * 2 + kst) * 2 + ab) * 64 + lane) * 8 + j0] = o;
}

// ---- prep: gather W1 (512x256) ----
__global__ void k_prep_w1(const float* __restrict__ src, unsigned short* __restrict__ dst) {
  int i = blockIdx.x * 256 + threadIdx.x;   // 32768 threads
  int j0 = (i & 1) * 4;
  int lane = (i >> 1) & 63;
  int kst = (i >> 7) & 15;
  int ct = (i >> 11) & 1;
  int wv = (i >> 12) & 7;
  int col = wv * 32 + ct * 16 + (lane & 15);
  int row = kst * 32 + (lane >> 4) * 8 + j0;
  ushort4 o;
  o.x = f2h(src[(size_t)(row + 0) * 256 + col]);
  o.y = f2h(src[(size_t)(row + 1) * 256 + col]);
  o.z = f2h(src[(size_t)(row + 2) * 256 + col]);
  o.w = f2h(src[(size_t)(row + 3) * 256 + col]);
  *(ushort4*)&dst[(size_t)(((wv * 2 + ct) * 16 + kst) * 64 + lane) * 8 + j0] = o;
}

// ---------- main: 16 entities/block, 8 waves = 8 heads, evo in 2 halves, f16 ----------
// Register-quantum model (r2..r12 evidence): per-wave alloc = (VGPR+AGPR) rounded to
// {64,128,256}; waves/SIMD = 512/quantum. launch_bounds(512,4) pins arch<=64; accs (~44)
// in AGPR keep total <=128 -> 4 waves/SIMD = 16 waves/CU (occ ~44%). Depth-1 prefetch
// added ONLY in score/agg loops (16 regs, shared live range) to stay inside the quantum.
__global__ __launch_bounds__(512, 4) void trust_main(
    const float* __restrict__ h_i, const float* __restrict__ evo,
    const float* __restrict__ var_i, const float* __restrict__ var_j,
    const float* __restrict__ bq, const float* __restrict__ bk, const float* __restrict__ bv,
    const float* __restrict__ ld, const float* __restrict__ b1,
    const float* __restrict__ W2, const float* __restrict__ b2,
    const unsigned short* __restrict__ wqA, const unsigned short* __restrict__ wkA,
    const unsigned short* __restrict__ wvA, const unsigned short* __restrict__ w1A,
    float* __restrict__ out) {
  __shared__ unsigned short evo_s[48 * EP];   // 49920 B, one half (8 ents x 6 w)
  __shared__ unsigned short qh_s[16 * EP];    // 16640 B, h -> pooled (16 rows)
  __shared__ float score_s[NH * BM * WW];     // 3072 B
  __shared__ float logit_s[BM * NH];          // 512 B
  __shared__ float conf_s[BM];                // 64 B
  // total 70208 B -> 2 blocks/CU

  const int t = threadIdx.x;
  const int wv = t >> 6;       // wave == head
  const int l = t & 63;
  const int l16 = l & 15;
  const int lq = l >> 4;
  const int e0 = blockIdx.x * BM;

  // decay bias
  float biasw[WW];
  {
    float rd = expf(ld[0]);
    float dsum = 0.f;
    #pragma unroll
    for (int w6 = 0; w6 < WW; ++w6) { biasw[w6] = expf(rd * (float)w6); dsum += biasw[w6]; }
    float dinv = 1.f / dsum;
    #pragma unroll
    for (int w6 = 0; w6 < WW; ++w6) biasw[w6] *= dinv;
  }

  const float4* ev4 = (const float4*)evo + (size_t)e0 * (WW * DD / 4);

  // ---- P0: stage evo half0 (ents 0-7) + h (16 rows) to LDS f16; conf ----
  {
    #pragma unroll 4
    for (int i = 0; i < 12; ++i) {
      int idx = i * 512 + t;
      int row = idx >> 7, c4 = idx & 127;
      float4 v = ev4[idx];
      uint2 o; o.x = pkrtz(v.x, v.y); o.y = pkrtz(v.z, v.w);
      *(uint2*)&evo_s[row * EP + c4 * 4] = o;
    }
    const float4* h4 = (const float4*)h_i + (size_t)e0 * (DD / 4);
    #pragma unroll
    for (int i = 0; i < 4; ++i) {
      int idx = i * 512 + t;
      int row = idx >> 7, c4 = idx & 127;
      float4 v = h4[idx];
      uint2 o; o.x = pkrtz(v.x, v.y); o.y = pkrtz(v.z, v.w);
      *(uint2*)&qh_s[row * EP + c4 * 4] = o;
    }
    int ce = t >> 5, cs = t & 31;
    const float4* vi4 = (const float4*)var_i + (size_t)(e0 + ce) * (DD / 4);
    const float4* vj4 = (const float4*)var_j + (size_t)(e0 + ce) * (DD / 4);
    float si = 0.f, sj = 0.f;
    #pragma unroll
    for (int i = 0; i < 4; ++i) {
      float4 a = vi4[i * 32 + cs]; si += a.x + a.y + a.z + a.w;
      float4 b = vj4[i * 32 + cs]; sj += b.x + b.y + b.z + b.w;
    }
    #pragma unroll
    for (int m = 1; m <= 16; m <<= 1) { si += __shfl_xor(si, m); sj += __shfl_xor(sj, m); }
    if (cs == 0) {
      float ci = 1.f / (1.f + fmaxf(sqrtf(si * (1.f / DD)), 1e-6f));
      float cj = 1.f / (1.f + fmaxf(sqrtf(sj * (1.f / DD)), 1e-6f));
      conf_s[ce] = fmaxf(0.5f * (logf(ci) + logf(cj)), -5.0f);
    }
  }
  __syncthreads();   // B1
  SCHED_FENCE();

  // ---- P1: Q^T per head (D rows = head-col, cols = 16 entities); Q stays in regs ----
  F16x8 qfr[2];      // qk B-frags, sigma slot order
  float qb;          // Q[e].bk at lane l16=e
  {
    f32x4 qacc[4] = {};
    const unsigned short* wqp = wqA + (size_t)wv * 4 * 16 * 512 + l * 8;
    #pragma unroll 2
    for (int kst = 0; kst < 16; ++kst) {
      f16x8 hb = *reinterpret_cast<const f16x8*>(&qh_s[l16 * EP + kst * 32 + lq * 8]);
      #pragma unroll
      for (int ct = 0; ct < 4; ++ct) {
        f16x8 a = *reinterpret_cast<const f16x8*>(&wqp[(ct * 16 + kst) * 512]);
        qacc[ct] = __builtin_amdgcn_mfma_f32_16x16x32_f16(a, hb, qacc[ct], 0, 0, 0);
      }
    }
    qb = 0.f;
    #pragma unroll
    for (int ct = 0; ct < 4; ++ct) {
      float4 bq4 = *(const float4*)&bq[wv * 64 + ct * 16 + lq * 4];
      float4 bk4 = *(const float4*)&bk[wv * 64 + ct * 16 + lq * 4];
      float q0 = qacc[ct][0] + bq4.x, q1 = qacc[ct][1] + bq4.y;
      float q2 = qacc[ct][2] + bq4.z, q3 = qacc[ct][3] + bq4.w;
      qb += q0 * bk4.x + q1 * bk4.y + q2 * bk4.z + q3 * bk4.w;
      qfr[ct >> 1].u[(ct & 1) * 2]     = pkrtz(q0, q1);
      qfr[ct >> 1].u[(ct & 1) * 2 + 1] = pkrtz(q2, q3);
    }
    qb += __shfl_xor(qb, 16);
    qb += __shfl_xor(qb, 32);   // lane l16=e holds qb[e]
  }
  SCHED_FENCE();

  f32x4 pacc[4] = {};   // pooled accumulator (spans both halves)
  const unsigned short* wkp = wkA + (size_t)wv * 16 * 2 * 2 * 512 + l * 8;
  const unsigned short* wvp = wvA + (size_t)wv * 4 * 16 * 512 + l * 8;

  #pragma unroll
  for (int H = 0; H < 2; ++H) {
    if (H == 1) {
      __syncthreads();   // B2: all waves done reading evo half0
      const float4* ev4b = ev4 + 6144;
      #pragma unroll 4
      for (int i = 0; i < 12; ++i) {
        int idx = i * 512 + t;
        int row = idx >> 7, c4 = idx & 127;
        float4 v = ev4b[idx];
        uint2 o; o.x = pkrtz(v.x, v.y); o.y = pkrtz(v.z, v.w);
        *(uint2*)&evo_s[row * EP + c4 * 4] = o;
      }
      __syncthreads();   // B3
    }

    // ---- score: Qk chunk -> af -> 3 evo MFMAs; depth-1 wrap prefetch on wkA ----
    f32x4 sacc0 = {}, sacc1 = {}, sacc2 = {};
    {
      F16x8 c00, c01, c10, c11, n00, n01, n10, n11;
      c00.v = *reinterpret_cast<const f16x8*>(&wkp[0 * 512]);
      c01.v = *reinterpret_cast<const f16x8*>(&wkp[1 * 512]);
      c10.v = *reinterpret_cast<const f16x8*>(&wkp[2 * 512]);
      c11.v = *reinterpret_cast<const f16x8*>(&wkp[3 * 512]);
      #pragma unroll 1
      for (int ch = 0; ch < 16; ++ch) {
        int nc = (ch + 1) & 15;   // wrap: always-valid address, no branch
        n00.v = *reinterpret_cast<const f16x8*>(&wkp[(nc * 4 + 0) * 512]);
        n01.v = *reinterpret_cast<const f16x8*>(&wkp[(nc * 4 + 1) * 512]);
        n10.v = *reinterpret_cast<const f16x8*>(&wkp[(nc * 4 + 2) * 512]);
        n11.v = *reinterpret_cast<const f16x8*>(&wkp[(nc * 4 + 3) * 512]);
        SCHED_FENCE();
        f32x4 qk0 = {}, qk1 = {};
        qk0 = __builtin_amdgcn_mfma_f32_16x16x32_f16(c00.v, qfr[0].v, qk0, 0, 0, 0);
        qk1 = __builtin_amdgcn_mfma_f32_16x16x32_f16(c01.v, qfr[0].v, qk1, 0, 0, 0);
        qk0 = __builtin_amdgcn_mfma_f32_16x16x32_f16(c10.v, qfr[1].v, qk0, 0, 0, 0);
        qk1 = __builtin_amdgcn_mfma_f32_16x16x32_f16(c11.v, qfr[1].v, qk1, 0, 0, 0);
        F16x8 af;
        af.u[0] = pkrtz(qk0[0], qk0[1]); af.u[1] = pkrtz(qk0[2], qk0[3]);
        af.u[2] = pkrtz(qk1[0], qk1[1]); af.u[3] = pkrtz(qk1[2], qk1[3]);
        int cb = ch * 32 + lq * 4;
        {
          F16x8 b; b.u2[0] = *(const uint2*)&evo_s[l16 * EP + cb];
          b.u2[1] = *(const uint2*)&evo_s[l16 * EP + cb + 16];
          sacc0 = __builtin_amdgcn_mfma_f32_16x16x32_f16(af.v, b.v, sacc0, 0, 0, 0);
        }
        {
          F16x8 b; b.u2[0] = *(const uint2*)&evo_s[(16 + l16) * EP + cb];
          b.u2[1] = *(const uint2*)&evo_s[(16 + l16) * EP + cb + 16];
          sacc1 = __builtin_amdgcn_mfma_f32_16x16x32_f16(af.v, b.v, sacc1, 0, 0, 0);
        }
        {
          F16x8 b; b.u2[0] = *(const uint2*)&evo_s[(32 + l16) * EP + cb];
          b.u2[1] = *(const uint2*)&evo_s[(32 + l16) * EP + cb + 16];
          sacc2 = __builtin_amdgcn_mfma_f32_16x16x32_f16(af.v, b.v, sacc2, 0, 0, 0);
        }
        c00 = n00; c01 = n01; c10 = n10; c11 = n11;
      }
    }
    SCHED_FENCE();

    // extract S[e][w]: D rows = entities, cols l16 -> half-local evo row L = 6*eL + w
    #pragma unroll
    for (int r = 0; r < 4; ++r) {
      int e = lq * 4 + r, eL = e - 8 * H;
      { int w = l16 - 6 * eL;      if (w >= 0 && w < WW) score_s[wv * 96 + e * 6 + w] = sacc0[r]; }
      { int w = 16 + l16 - 6 * eL; if (w >= 0 && w < WW) score_s[wv * 96 + e * 6 + w] = sacc1[r]; }
      { int w = 32 + l16 - 6 * eL; if (w >= 0 && w < WW) score_s[wv * 96 + e * 6 + w] = sacc2[r]; }
    }
    // softmax for this half's entities (attn written back by l16==0 lanes)
    #pragma unroll
    for (int r = 0; r < 4; ++r) {
      int e = lq * 4 + r, eL = e - 8 * H;
      if (eL >= 0 && eL < 8) {
        float qbv = __shfl(qb, e);
        float sc[WW]; float mx = -1e30f;
        #pragma unroll
        for (int w6 = 0; w6 < WW; ++w6) {
          sc[w6] = 0.125f * (score_s[wv * 96 + e * 6 + w6] + qbv) + biasw[w6];
          mx = fmaxf(mx, sc[w6]);
        }
        float ssum = 0.f;
        #pragma unroll
        for (int w6 = 0; w6 < WW; ++w6) { sc[w6] = expf(sc[w6] - mx); ssum += sc[w6]; }
        float sinv = 1.f / ssum;
        if (l16 == 0) {
          #pragma unroll
          for (int w6 = 0; w6 < WW; ++w6) score_s[wv * 96 + e * 6 + w6] = sc[w6] * sinv;
        }
      }
    }
    SCHED_FENCE();

    // ---- agg via hfma2 (lane = entity l16); depth-1 wrap prefetch on wvA ----
    {
      __half2 aw2[WW];
      bool inh = ((l16 >> 3) == H);
      #pragma unroll
      for (int w6 = 0; w6 < WW; ++w6) {
        float v = score_s[wv * 96 + l16 * 6 + w6];
        v = inh ? v : 0.f;
        H2U a; a.u = pkrtz(v, v); aw2[w6] = a.h;
      }
      const int arow = (l16 & 7) * 6;
      F16x8 cv0, cv1, cv2, cv3, nv0, nv1, nv2, nv3;
      cv0.v = *reinterpret_cast<const f16x8*>(&wvp[(0 * 16 + 0) * 512]);
      cv1.v = *reinterpret_cast<const f16x8*>(&wvp[(1 * 16 + 0) * 512]);
      cv2.v = *reinterpret_cast<const f16x8*>(&wvp[(2 * 16 + 0) * 512]);
      cv3.v = *reinterpret_cast<const f16x8*>(&wvp[(3 * 16 + 0) * 512]);
      #pragma unroll 1
      for (int ch = 0; ch < 16; ++ch) {
        int nc = (ch + 1) & 15;
        nv0.v = *reinterpret_cast<const f16x8*>(&wvp[(0 * 16 + nc) * 512]);
        nv1.v = *reinterpret_cast<const f16x8*>(&wvp[(1 * 16 + nc) * 512]);
        nv2.v = *reinterpret_cast<const f16x8*>(&wvp[(2 * 16 + nc) * 512]);
        nv3.v = *reinterpret_cast<const f16x8*>(&wvp[(3 * 16 + nc) * 512]);
        SCHED_FENCE();
        H2U z; z.u = 0;
        __half2 ac0 = z.h, ac1 = z.h, ac2 = z.h, ac3 = z.h;
        #pragma unroll
        for (int w6 = 0; w6 < WW; ++w6) {
          U4H vv; vv.q = *(const uint4*)&evo_s[(arow + w6) * EP + ch * 32 + lq * 8];
          ac0 = __hfma2(vv.h[0], aw2[w6], ac0);
          ac1 = __hfma2(vv.h[1], aw2[w6], ac1);
          ac2 = __hfma2(vv.h[2], aw2[w6], ac2);
          ac3 = __hfma2(vv.h[3], aw2[w6], ac3);
        }
        F16x8 af;
        { H2U c; c.h = ac0; af.u[0] = c.u; c.h = ac1; af.u[1] = c.u;
          c.h = ac2; af.u[2] = c.u; c.h = ac3; af.u[3] = c.u; }
        pacc[0] = __builtin_amdgcn_mfma_f32_16x16x32_f16(af.v, cv0.v, pacc[0], 0, 0, 0);
        pacc[1] = __builtin_amdgcn_mfma_f32_16x16x32_f16(af.v, cv1.v, pacc[1], 0, 0, 0);
        pacc[2] = __builtin_amdgcn_mfma_f32_16x16x32_f16(af.v, cv2.v, pacc[2], 0, 0, 0);
        pacc[3] = __builtin_amdgcn_mfma_f32_16x16x32_f16(af.v, cv3.v, pacc[3], 0, 0, 0);
        cv0 = nv0; cv1 = nv1; cv2 = nv2; cv3 = nv3;
      }
    }
  }

  // pooled -> qh_s (f16)
  #pragma unroll
  for (int ct = 0; ct < 4; ++ct) {
    int col = wv * 64 + ct * 16 + l16;
    float bvv = bv[col];
    #pragma unroll
    for (int r = 0; r < 4; ++r)
      qh_s[(lq * 4 + r) * EP + col] = f2h(pacc[ct][r] + bvv);
  }
  __syncthreads();   // B4

  // ---- P6: hmid = gelu(pooled @ W1 + b1); logit partials ----
  {
    f32x4 hacc[2] = {};
    const unsigned short* w1p = w1A + (size_t)wv * 2 * 16 * 512 + l * 8;
    #pragma unroll 2
    for (int kst = 0; kst < 16; ++kst) {
      f16x8 a = *reinterpret_cast<const f16x8*>(&qh_s[l16 * EP + kst * 32 + lq * 8]);
      #pragma unroll
      for (int ct = 0; ct < 2; ++ct) {
        f16x8 b = *reinterpret_cast<const f16x8*>(&w1p[(ct * 16 + kst) * 512]);
        hacc[ct] = __builtin_amdgcn_mfma_f32_16x16x32_f16(a, b, hacc[ct], 0, 0, 0);
      }
    }
    float lg[4] = {0.f, 0.f, 0.f, 0.f};
    #pragma unroll
    for (int ct = 0; ct < 2; ++ct) {
      int m = wv * 32 + ct * 16 + l16;
      float b1v = b1[m], w2v = W2[m];
      #pragma unroll
      for (int r = 0; r < 4; ++r) {
        float x = hacc[ct][r] + b1v;
        float g = 0.5f * x * (1.f + erff(x * 0.70710678118f));
        lg[r] += g * w2v;
      }
    }
    #pragma unroll
    for (int r = 0; r < 4; ++r) {
      #pragma unroll
      for (int m = 1; m <= 8; m <<= 1) lg[r] += __shfl_xor(lg[r], m);
    }
    if (l16 == 0) {
      #pragma unroll
      for (int r = 0; r < 4; ++r) logit_s[(lq * 4 + r) * NH + wv] = lg[r];
    }
  }
  __syncthreads();   // B5

  // ---- P7: combine + sigmoid ----
  if (t < BM) {
    float s = 0.f;
    #pragma unroll
    for (int w8 = 0; w8 < NH; ++w8) s += logit_s[t * NH + w8];
    s += b2[0] + conf_s[t];
    out[e0 + t] = 1.f / (1.f + expf(-s));
  }
}

extern "C" void kernel_launch(void* const* d_in, const int* in_sizes, int n_in,
                              void* d_out, int out_size, void* d_ws, size_t ws_size,
                              hipStream_t stream) {
  (void)in_sizes; (void)n_in; (void)out_size; (void)ws_size;
  const float* h_i = (const float*)d_in[0];
  const float* evo = (const float*)d_in[1];
  const float* vi  = (const float*)d_in[2];
  const float* vj  = (const float*)d_in[3];
  const float* Wq  = (const float*)d_in[4];
  const float* bq  = (const float*)d_in[5];
  const float* Wk  = (const float*)d_in[6];
  const float* bk  = (const float*)d_in[7];
  const float* Wv  = (const float*)d_in[8];
  const float* bv  = (const float*)d_in[9];
  const float* ld  = (const float*)d_in[10];
  const float* W1  = (const float*)d_in[11];
  const float* b1  = (const float*)d_in[12];
  const float* W2  = (const float*)d_in[13];
  const float* b2  = (const float*)d_in[14];
  float* out = (float*)d_out;

  unsigned short* ws  = (unsigned short*)d_ws;
  unsigned short* wqA = ws;            // 512KB f16, Wq fragment-order
  unsigned short* wkA = ws + 262144;   // 512KB f16, Wk qk-A-frag order
  unsigned short* wvA = ws + 524288;   // 512KB f16, Wv B-frag order
  unsigned short* w1A = ws + 786432;   // 256KB f16, W1 B-frag order

  k_prep_qv<<<256, 256, 0, stream>>>(Wq, wqA);
  k_prep_wk<<<256, 256, 0, stream>>>(Wk, wkA);
  k_prep_qv<<<256, 256, 0, stream>>>(Wv, wvA);
  k_prep_w1<<<128, 256, 0, stream>>>(W1, w1A);
  trust_main<<<3125, 512, 0, stream>>>(h_i, evo, vi, vj, bq, bk, bv, ld, b1, W2, b2,
                                       wqA, wkA, wvA, w1A, out);
}

// Round 14
// 411.133 us; speedup vs baseline: 1.6672x; 1.2101x over previous
//
#include <hip/hip_runtime.h>
#include <hip/hip_fp16.h>

typedef _Float16 f16;
typedef _Float16 f16x8 __attribute__((ext_vector_type(8)));
typedef __fp16 fp16x2_raw __attribute__((ext_vector_type(2)));
typedef float f32x4 __attribute__((ext_vector_type(4)));

#define DD 512
#define BM 16     // entities per block
#define WW 6
#define NH 8
#define EPQ 520   // qh LDS row stride (f16)
#define EPE 264   // evo LDS row stride (f16): 256 cols + 8 pad -> rows +4 banks

union F16x8 { f16x8 v; unsigned u[4]; uint2 u2[2]; };
union H2U { __half2 h; unsigned u; };
union U4H { uint4 q; __half2 h[4]; };

__device__ __forceinline__ unsigned pkrtz(float a, float b) {
  union { fp16x2_raw h; unsigned u; } c;
  c.h = __builtin_amdgcn_cvt_pkrtz(a, b);
  return c.u;
}
__device__ __forceinline__ unsigned short f2h(float x) {
  union { f16 h; unsigned short u; } c; c.h = (f16)x; return c.u;
}
#define SCHED_FENCE() __builtin_amdgcn_sched_barrier(0)

// ---- prep: gather Wq/Wv (512x512) into per-(head,ct,kst) A/B fragment-order, f16 ----
__global__ void k_prep_qv(const float* __restrict__ src, unsigned short* __restrict__ dst) {
  int i = blockIdx.x * 256 + threadIdx.x;   // 65536 threads, 4 j each
  int j0 = (i & 1) * 4;
  int lane = (i >> 1) & 63;
  int kst = (i >> 7) & 15;
  int ct = (i >> 11) & 3;
  int wv = (i >> 13) & 7;
  int col = wv * 64 + ct * 16 + (lane & 15);
  int row = kst * 32 + (lane >> 4) * 8 + j0;
  ushort4 o;
  o.x = f2h(src[(size_t)(row + 0) * DD + col]);
  o.y = f2h(src[(size_t)(row + 1) * DD + col]);
  o.z = f2h(src[(size_t)(row + 2) * DD + col]);
  o.w = f2h(src[(size_t)(row + 3) * DD + col]);
  *(ushort4*)&dst[(size_t)(((wv * 4 + ct) * 16 + kst) * 64 + lane) * 8 + j0] = o;
}

// ---- prep: gather Wk into qk-A-frag order (sigma slot permutation baked in) ----
__global__ void k_prep_wk(const float* __restrict__ src, unsigned short* __restrict__ dst) {
  int i = blockIdx.x * 256 + threadIdx.x;   // 65536 threads
  int j0 = (i & 1) * 4;
  int lane = (i >> 1) & 63;
  int ab = (i >> 7) & 1;
  int kst = (i >> 8) & 1;
  int ch = (i >> 9) & 15;
  int wv = (i >> 13) & 7;
  int row = ch * 32 + ab * 16 + (lane & 15);
  int cb = wv * 64 + kst * 32 + (j0 ? 16 : 0) + ((lane >> 4) & 3) * 4;
  float4 v = *(const float4*)&src[(size_t)row * DD + cb];
  ushort4 o; o.x = f2h(v.x); o.y = f2h(v.y); o.z = f2h(v.z); o.w = f2h(v.w);
  *(ushort4*)&dst[(size_t)((((wv * 16 + ch) * 2 + kst) * 2 + ab) * 64 + lane) * 8 + j0] = o;
}

// ---- prep: gather W1 (512x256) ----
__global__ void k_prep_w1(const float* __restrict__ src, unsigned short* __restrict__ dst) {
  int i = blockIdx.x * 256 + threadIdx.x;   // 32768 threads
  int j0 = (i & 1) * 4;
  int lane = (i >> 1) & 63;
  int kst = (i >> 7) & 15;
  int ct = (i >> 11) & 1;
  int wv = (i >> 12) & 7;
  int col = wv * 32 + ct * 16 + (lane & 15);
  int row = kst * 32 + (lane >> 4) * 8 + j0;
  ushort4 o;
  o.x = f2h(src[(size_t)(row + 0) * 256 + col]);
  o.y = f2h(src[(size_t)(row + 1) * 256 + col]);
  o.z = f2h(src[(size_t)(row + 2) * 256 + col]);
  o.w = f2h(src[(size_t)(row + 3) * 256 + col]);
  *(ushort4*)&dst[(size_t)(((wv * 2 + ct) * 16 + kst) * 64 + lane) * 8 + j0] = o;
}

// ---------- main: 16 entities/block, 8 waves = 8 heads, evo split by K-COLUMNS ----------
// r13 diagnosis: L2 weight stream (2.75MB/block incl. 1.0MB recompute) ~50% of wall; agg
// half-lane waste 2x. K-split: evo_s = ALL 96 rows x 256 cols -> wk/wv read ONCE (sacc/pacc
// accumulate across K-halves), agg uses all 16 lanes. Cost: one evo K-half restage (HBM has
// 8x headroom). Register quantum model: arch<=64 (launch_bounds(512,4)) + ~40 AGPR <= 128.
__global__ __launch_bounds__(512, 4) void trust_main(
    const float* __restrict__ h_i, const float* __restrict__ evo,
    const float* __restrict__ var_i, const float* __restrict__ var_j,
    const float* __restrict__ bq, const float* __restrict__ bk, const float* __restrict__ bv,
    const float* __restrict__ ld, const float* __restrict__ b1,
    const float* __restrict__ W2, const float* __restrict__ b2,
    const unsigned short* __restrict__ wqA, const unsigned short* __restrict__ wkA,
    const unsigned short* __restrict__ wvA, const unsigned short* __restrict__ w1A,
    float* __restrict__ out) {
  __shared__ unsigned short evo_s[96 * EPE];  // 50688 B, one K-half of all 96 rows
  __shared__ unsigned short qh_s[16 * EPQ];   // 16640 B, h -> pooled
  __shared__ float score_s[NH * BM * WW];     // 3072 B
  __shared__ float logit_s[BM * NH];          // 512 B
  __shared__ float conf_s[BM];                // 64 B
  // total 70976 B -> 2 blocks/CU

  const int t = threadIdx.x;
  const int wv = t >> 6;       // wave == head
  const int l = t & 63;
  const int l16 = l & 15;
  const int lq = l >> 4;
  const int e0 = blockIdx.x * BM;

  // decay bias
  float biasw[WW];
  {
    float rd = expf(ld[0]);
    float dsum = 0.f;
    #pragma unroll
    for (int w6 = 0; w6 < WW; ++w6) { biasw[w6] = expf(rd * (float)w6); dsum += biasw[w6]; }
    float dinv = 1.f / dsum;
    #pragma unroll
    for (int w6 = 0; w6 < WW; ++w6) biasw[w6] *= dinv;
  }

  const float4* ev4 = (const float4*)evo + (size_t)e0 * (WW * DD / 4);

  // ---- P0: stage evo K-half0 (cols 0-255, all 96 rows) + h (16 rows); conf ----
  {
    #pragma unroll 4
    for (int i = 0; i < 12; ++i) {
      int idx = i * 512 + t;
      int row = idx >> 6, c4 = idx & 63;   // 64 float4 per row-half
      float4 v = ev4[row * 128 + c4];
      uint2 o; o.x = pkrtz(v.x, v.y); o.y = pkrtz(v.z, v.w);
      *(uint2*)&evo_s[row * EPE + c4 * 4] = o;
    }
    const float4* h4 = (const float4*)h_i + (size_t)e0 * (DD / 4);
    #pragma unroll
    for (int i = 0; i < 4; ++i) {
      int idx = i * 512 + t;
      int row = idx >> 7, c4 = idx & 127;
      float4 v = h4[idx];
      uint2 o; o.x = pkrtz(v.x, v.y); o.y = pkrtz(v.z, v.w);
      *(uint2*)&qh_s[row * EPQ + c4 * 4] = o;
    }
    int ce = t >> 5, cs = t & 31;
    const float4* vi4 = (const float4*)var_i + (size_t)(e0 + ce) * (DD / 4);
    const float4* vj4 = (const float4*)var_j + (size_t)(e0 + ce) * (DD / 4);
    float si = 0.f, sj = 0.f;
    #pragma unroll
    for (int i = 0; i < 4; ++i) {
      float4 a = vi4[i * 32 + cs]; si += a.x + a.y + a.z + a.w;
      float4 b = vj4[i * 32 + cs]; sj += b.x + b.y + b.z + b.w;
    }
    #pragma unroll
    for (int m = 1; m <= 16; m <<= 1) { si += __shfl_xor(si, m); sj += __shfl_xor(sj, m); }
    if (cs == 0) {
      float ci = 1.f / (1.f + fmaxf(sqrtf(si * (1.f / DD)), 1e-6f));
      float cj = 1.f / (1.f + fmaxf(sqrtf(sj * (1.f / DD)), 1e-6f));
      conf_s[ce] = fmaxf(0.5f * (logf(ci) + logf(cj)), -5.0f);
    }
  }
  __syncthreads();   // B1
  SCHED_FENCE();

  // ---- P1: Q^T per head (full 512-wide h from qh_s); Q stays in regs ----
  F16x8 qfr[2];      // qk B-frags, sigma slot order
  float qb;          // Q[e].bk at lane l16=e
  {
    f32x4 qacc[4] = {};
    const unsigned short* wqp = wqA + (size_t)wv * 4 * 16 * 512 + l * 8;
    #pragma unroll 2
    for (int kst = 0; kst < 16; ++kst) {
      f16x8 hb = *reinterpret_cast<const f16x8*>(&qh_s[l16 * EPQ + kst * 32 + lq * 8]);
      #pragma unroll
      for (int ct = 0; ct < 4; ++ct) {
        f16x8 a = *reinterpret_cast<const f16x8*>(&wqp[(ct * 16 + kst) * 512]);
        qacc[ct] = __builtin_amdgcn_mfma_f32_16x16x32_f16(a, hb, qacc[ct], 0, 0, 0);
      }
    }
    qb = 0.f;
    #pragma unroll
    for (int ct = 0; ct < 4; ++ct) {
      float4 bq4 = *(const float4*)&bq[wv * 64 + ct * 16 + lq * 4];
      float4 bk4 = *(const float4*)&bk[wv * 64 + ct * 16 + lq * 4];
      float q0 = qacc[ct][0] + bq4.x, q1 = qacc[ct][1] + bq4.y;
      float q2 = qacc[ct][2] + bq4.z, q3 = qacc[ct][3] + bq4.w;
      qb += q0 * bk4.x + q1 * bk4.y + q2 * bk4.z + q3 * bk4.w;
      qfr[ct >> 1].u[(ct & 1) * 2]     = pkrtz(q0, q1);
      qfr[ct >> 1].u[(ct & 1) * 2 + 1] = pkrtz(q2, q3);
    }
    qb += __shfl_xor(qb, 16);
    qb += __shfl_xor(qb, 32);   // lane l16=e holds qb[e]
  }
  SCHED_FENCE();

  // ---- score: accumulate S over both K-halves; wk read ONCE ----
  f32x4 sacc0 = {}, sacc1 = {}, sacc2 = {}, sacc3 = {}, sacc4 = {}, sacc5 = {};
  const unsigned short* wkp = wkA + (size_t)wv * 16 * 2 * 2 * 512 + l * 8;
  const unsigned short* wvp = wvA + (size_t)wv * 4 * 16 * 512 + l * 8;

  #pragma unroll
  for (int KH = 0; KH < 2; ++KH) {
    if (KH == 1) {
      __syncthreads();   // B2: all waves done with K-half0 score reads
      #pragma unroll 4
      for (int i = 0; i < 12; ++i) {
        int idx = i * 512 + t;
        int row = idx >> 6, c4 = idx & 63;
        float4 v = ev4[row * 128 + 64 + c4];
        uint2 o; o.x = pkrtz(v.x, v.y); o.y = pkrtz(v.z, v.w);
        *(uint2*)&evo_s[row * EPE + c4 * 4] = o;
      }
      __syncthreads();   // B3
    }
    {
      const unsigned short* wkb = wkp + (size_t)(KH * 8) * 4 * 512;
      F16x8 c00, c01, c10, c11, n00, n01, n10, n11;
      c00.v = *reinterpret_cast<const f16x8*>(&wkb[0 * 512]);
      c01.v = *reinterpret_cast<const f16x8*>(&wkb[1 * 512]);
      c10.v = *reinterpret_cast<const f16x8*>(&wkb[2 * 512]);
      c11.v = *reinterpret_cast<const f16x8*>(&wkb[3 * 512]);
      #pragma unroll 1
      for (int ci = 0; ci < 8; ++ci) {
        int nl = (ci + 1) & 7;   // wrap prefetch, always-valid
        n00.v = *reinterpret_cast<const f16x8*>(&wkb[(nl * 4 + 0) * 512]);
        n01.v = *reinterpret_cast<const f16x8*>(&wkb[(nl * 4 + 1) * 512]);
        n10.v = *reinterpret_cast<const f16x8*>(&wkb[(nl * 4 + 2) * 512]);
        n11.v = *reinterpret_cast<const f16x8*>(&wkb[(nl * 4 + 3) * 512]);
        SCHED_FENCE();
        f32x4 qk0 = {}, qk1 = {};
        qk0 = __builtin_amdgcn_mfma_f32_16x16x32_f16(c00.v, qfr[0].v, qk0, 0, 0, 0);
        qk1 = __builtin_amdgcn_mfma_f32_16x16x32_f16(c01.v, qfr[0].v, qk1, 0, 0, 0);
        qk0 = __builtin_amdgcn_mfma_f32_16x16x32_f16(c10.v, qfr[1].v, qk0, 0, 0, 0);
        qk1 = __builtin_amdgcn_mfma_f32_16x16x32_f16(c11.v, qfr[1].v, qk1, 0, 0, 0);
        F16x8 af;
        af.u[0] = pkrtz(qk0[0], qk0[1]); af.u[1] = pkrtz(qk0[2], qk0[3]);
        af.u[2] = pkrtz(qk1[0], qk1[1]); af.u[3] = pkrtz(qk1[2], qk1[3]);
        int cb = ci * 32 + lq * 4;   // local col within K-half
        {
          F16x8 b; b.u2[0] = *(const uint2*)&evo_s[(0 * 16 + l16) * EPE + cb];
          b.u2[1] = *(const uint2*)&evo_s[(0 * 16 + l16) * EPE + cb + 16];
          sacc0 = __builtin_amdgcn_mfma_f32_16x16x32_f16(af.v, b.v, sacc0, 0, 0, 0);
        }
        {
          F16x8 b; b.u2[0] = *(const uint2*)&evo_s[(1 * 16 + l16) * EPE + cb];
          b.u2[1] = *(const uint2*)&evo_s[(1 * 16 + l16) * EPE + cb + 16];
          sacc1 = __builtin_amdgcn_mfma_f32_16x16x32_f16(af.v, b.v, sacc1, 0, 0, 0);
        }
        {
          F16x8 b; b.u2[0] = *(const uint2*)&evo_s[(2 * 16 + l16) * EPE + cb];
          b.u2[1] = *(const uint2*)&evo_s[(2 * 16 + l16) * EPE + cb + 16];
          sacc2 = __builtin_amdgcn_mfma_f32_16x16x32_f16(af.v, b.v, sacc2, 0, 0, 0);
        }
        {
          F16x8 b; b.u2[0] = *(const uint2*)&evo_s[(3 * 16 + l16) * EPE + cb];
          b.u2[1] = *(const uint2*)&evo_s[(3 * 16 + l16) * EPE + cb + 16];
          sacc3 = __builtin_amdgcn_mfma_f32_16x16x32_f16(af.v, b.v, sacc3, 0, 0, 0);
        }
        {
          F16x8 b; b.u2[0] = *(const uint2*)&evo_s[(4 * 16 + l16) * EPE + cb];
          b.u2[1] = *(const uint2*)&evo_s[(4 * 16 + l16) * EPE + cb + 16];
          sacc4 = __builtin_amdgcn_mfma_f32_16x16x32_f16(af.v, b.v, sacc4, 0, 0, 0);
        }
        {
          F16x8 b; b.u2[0] = *(const uint2*)&evo_s[(5 * 16 + l16) * EPE + cb];
          b.u2[1] = *(const uint2*)&evo_s[(5 * 16 + l16) * EPE + cb + 16];
          sacc5 = __builtin_amdgcn_mfma_f32_16x16x32_f16(af.v, b.v, sacc5, 0, 0, 0);
        }
        c00 = n00; c01 = n01; c10 = n10; c11 = n11;
      }
    }
  }
  SCHED_FENCE();

  // ---- extract S[e][w]: D rows = entities (e=lq*4+r), cols l16 -> evo row L = 6e+w ----
  #pragma unroll
  for (int r = 0; r < 4; ++r) {
    int e = lq * 4 + r;
    int base = l16 - 6 * e;
    { int w = base;      if (w >= 0 && w < WW) score_s[wv * 96 + e * 6 + w] = sacc0[r]; }
    { int w = base + 16; if (w >= 0 && w < WW) score_s[wv * 96 + e * 6 + w] = sacc1[r]; }
    { int w = base + 32; if (w >= 0 && w < WW) score_s[wv * 96 + e * 6 + w] = sacc2[r]; }
    { int w = base + 48; if (w >= 0 && w < WW) score_s[wv * 96 + e * 6 + w] = sacc3[r]; }
    { int w = base + 64; if (w >= 0 && w < WW) score_s[wv * 96 + e * 6 + w] = sacc4[r]; }
    { int w = base + 80; if (w >= 0 && w < WW) score_s[wv * 96 + e * 6 + w] = sacc5[r]; }
  }
  // softmax, all 16 entities (attn written back by l16==0 lanes; same-wave LDS order)
  #pragma unroll
  for (int r = 0; r < 4; ++r) {
    int e = lq * 4 + r;
    float qbv = __shfl(qb, e);
    float sc[WW]; float mx = -1e30f;
    #pragma unroll
    for (int w6 = 0; w6 < WW; ++w6) {
      sc[w6] = 0.125f * (score_s[wv * 96 + e * 6 + w6] + qbv) + biasw[w6];
      mx = fmaxf(mx, sc[w6]);
    }
    float ssum = 0.f;
    #pragma unroll
    for (int w6 = 0; w6 < WW; ++w6) { sc[w6] = expf(sc[w6] - mx); ssum += sc[w6]; }
    float sinv = 1.f / ssum;
    if (l16 == 0) {
      #pragma unroll
      for (int w6 = 0; w6 < WW; ++w6) score_s[wv * 96 + e * 6 + w6] = sc[w6] * sinv;
    }
  }
  SCHED_FENCE();

  // ---- agg + pooled over K-halves (KH1 resident first, then restage KH0); wv ONCE ----
  f32x4 pacc[4] = {};
  {
    __half2 aw2[WW];
    #pragma unroll
    for (int w6 = 0; w6 < WW; ++w6) {
      float v = score_s[wv * 96 + l16 * 6 + w6];   // all 16 lanes valid
      H2U a; a.u = pkrtz(v, v); aw2[w6] = a.h;
    }
    const int arow = l16 * 6;
    #pragma unroll
    for (int KH2 = 1; KH2 >= 0; --KH2) {
      if (KH2 == 0) {
        __syncthreads();   // B4: all waves done with K-half1 agg reads
        #pragma unroll 4
        for (int i = 0; i < 12; ++i) {
          int idx = i * 512 + t;
          int row = idx >> 6, c4 = idx & 63;
          float4 v = ev4[row * 128 + c4];   // restage K-half0
          uint2 o; o.x = pkrtz(v.x, v.y); o.y = pkrtz(v.z, v.w);
          *(uint2*)&evo_s[row * EPE + c4 * 4] = o;
        }
        __syncthreads();   // B5
      }
      F16x8 cv0, cv1, cv2, cv3, nv0, nv1, nv2, nv3;
      cv0.v = *reinterpret_cast<const f16x8*>(&wvp[(0 * 16 + KH2 * 8) * 512]);
      cv1.v = *reinterpret_cast<const f16x8*>(&wvp[(1 * 16 + KH2 * 8) * 512]);
      cv2.v = *reinterpret_cast<const f16x8*>(&wvp[(2 * 16 + KH2 * 8) * 512]);
      cv3.v = *reinterpret_cast<const f16x8*>(&wvp[(3 * 16 + KH2 * 8) * 512]);
      #pragma unroll 1
      for (int ci = 0; ci < 8; ++ci) {
        int nl = KH2 * 8 + ((ci + 1) & 7);
        nv0.v = *reinterpret_cast<const f16x8*>(&wvp[(0 * 16 + nl) * 512]);
        nv1.v = *reinterpret_cast<const f16x8*>(&wvp[(1 * 16 + nl) * 512]);
        nv2.v = *reinterpret_cast<const f16x8*>(&wvp[(2 * 16 + nl) * 512]);
        nv3.v = *reinterpret_cast<const f16x8*>(&wvp[(3 * 16 + nl) * 512]);
        SCHED_FENCE();
        H2U z; z.u = 0;
        __half2 ac0 = z.h, ac1 = z.h, ac2 = z.h, ac3 = z.h;
        #pragma unroll
        for (int w6 = 0; w6 < WW; ++w6) {
          U4H vv; vv.q = *(const uint4*)&evo_s[(arow + w6) * EPE + ci * 32 + lq * 8];
          ac0 = __hfma2(vv.h[0], aw2[w6], ac0);
          ac1 = __hfma2(vv.h[1], aw2[w6], ac1);
          ac2 = __hfma2(vv.h[2], aw2[w6], ac2);
          ac3 = __hfma2(vv.h[3], aw2[w6], ac3);
        }
        F16x8 af;
        { H2U c; c.h = ac0; af.u[0] = c.u; c.h = ac1; af.u[1] = c.u;
          c.h = ac2; af.u[2] = c.u; c.h = ac3; af.u[3] = c.u; }
        pacc[0] = __builtin_amdgcn_mfma_f32_16x16x32_f16(af.v, cv0.v, pacc[0], 0, 0, 0);
        pacc[1] = __builtin_amdgcn_mfma_f32_16x16x32_f16(af.v, cv1.v, pacc[1], 0, 0, 0);
        pacc[2] = __builtin_amdgcn_mfma_f32_16x16x32_f16(af.v, cv2.v, pacc[2], 0, 0, 0);
        pacc[3] = __builtin_amdgcn_mfma_f32_16x16x32_f16(af.v, cv3.v, pacc[3], 0, 0, 0);
        cv0 = nv0; cv1 = nv1; cv2 = nv2; cv3 = nv3;
      }
    }
  }

  // pooled -> qh_s (f16); h is dead since P1, no concurrent readers
  #pragma unroll
  for (int ct = 0; ct < 4; ++ct) {
    int col = wv * 64 + ct * 16 + l16;
    float bvv = bv[col];
    #pragma unroll
    for (int r = 0; r < 4; ++r)
      qh_s[(lq * 4 + r) * EPQ + col] = f2h(pacc[ct][r] + bvv);
  }
  __syncthreads();   // B6

  // ---- P6: hmid = gelu(pooled @ W1 + b1); logit partials ----
  {
    f32x4 hacc[2] = {};
    const unsigned short* w1p = w1A + (size_t)wv * 2 * 16 * 512 + l * 8;
    #pragma unroll 2
    for (int kst = 0; kst < 16; ++kst) {
      f16x8 a = *reinterpret_cast<const f16x8*>(&qh_s[l16 * EPQ + kst * 32 + lq * 8]);
      #pragma unroll
      for (int ct = 0; ct < 2; ++ct) {
        f16x8 b = *reinterpret_cast<const f16x8*>(&w1p[(ct * 16 + kst) * 512]);
        hacc[ct] = __builtin_amdgcn_mfma_f32_16x16x32_f16(a, b, hacc[ct], 0, 0, 0);
      }
    }
    float lg[4] = {0.f, 0.f, 0.f, 0.f};
    #pragma unroll
    for (int ct = 0; ct < 2; ++ct) {
      int m = wv * 32 + ct * 16 + l16;
      float b1v = b1[m], w2v = W2[m];
      #pragma unroll
      for (int r = 0; r < 4; ++r) {
        float x = hacc[ct][r] + b1v;
        float g = 0.5f * x * (1.f + erff(x * 0.70710678118f));
        lg[r] += g * w2v;
      }
    }
    #pragma unroll
    for (int r = 0; r < 4; ++r) {
      #pragma unroll
      for (int m = 1; m <= 8; m <<= 1) lg[r] += __shfl_xor(lg[r], m);
    }
    if (l16 == 0) {
      #pragma unroll
      for (int r = 0; r < 4; ++r) logit_s[(lq * 4 + r) * NH + wv] = lg[r];
    }
  }
  __syncthreads();   // B7

  // ---- P7: combine + sigmoid ----
  if (t < BM) {
    float s = 0.f;
    #pragma unroll
    for (int w8 = 0; w8 < NH; ++w8) s += logit_s[t * NH + w8];
    s += b2[0] + conf_s[t];
    out[e0 + t] = 1.f / (1.f + expf(-s));
  }
}

extern "C" void kernel_launch(void* const* d_in, const int* in_sizes, int n_in,
                              void* d_out, int out_size, void* d_ws, size_t ws_size,
                              hipStream_t stream) {
  (void)in_sizes; (void)n_in; (void)out_size; (void)ws_size;
  const float* h_i = (const float*)d_in[0];
  const float* evo = (const float*)d_in[1];
  const float* vi  = (const float*)d_in[2];
  const float* vj  = (const float*)d_in[3];
  const float* Wq  = (const float*)d_in[4];
  const float* bq  = (const float*)d_in[5];
  const float* Wk  = (const float*)d_in[6];
  const float* bk  = (const float*)d_in[7];
  const float* Wv  = (const float*)d_in[8];
  const float* bv  = (const float*)d_in[9];
  const float* ld  = (const float*)d_in[10];
  const float* W1  = (const float*)d_in[11];
  const float* b1  = (const float*)d_in[12];
  const float* W2  = (const float*)d_in[13];
  const float* b2  = (const float*)d_in[14];
  float* out = (float*)d_out;

  unsigned short* ws  = (unsigned short*)d_ws;
  unsigned short* wqA = ws;            // 512KB f16, Wq fragment-order
  unsigned short* wkA = ws + 262144;   // 512KB f16, Wk qk-A-frag order
  unsigned short* wvA = ws + 524288;   // 512KB f16, Wv B-frag order
  unsigned short* w1A = ws + 786432;   // 256KB f16, W1 B-frag order

  k_prep_qv<<<256, 256, 0, stream>>>(Wq, wqA);
  k_prep_wk<<<256, 256, 0, stream>>>(Wk, wkA);
  k_prep_qv<<<256, 256, 0, stream>>>(Wv, wvA);
  k_prep_w1<<<128, 256, 0, stream>>>(W1, w1A);
  trust_main<<<3125, 512, 0, stream>>>(h_i, evo, vi, vj, bq, bk, bv, ld, b1, W2, b2,
                                       wqA, wkA, wvA, w1A, out);
}

// Round 15
// 362.592 us; speedup vs baseline: 1.8904x; 1.1339x over previous
//
#include <hip/hip_runtime.h>
#include <hip/hip_fp16.h>

typedef _Float16 f16;
typedef _Float16 f16x8 __attribute__((ext_vector_type(8)));
typedef __fp16 fp16x2_raw __attribute__((ext_vector_type(2)));
typedef float f32x4 __attribute__((ext_vector_type(4)));

#define DD 512
#define BM 32     // entities per block (2 MFMA groups of 16 per wave)
#define WW 6
#define NH 8
#define QS 520    // qh/pooled LDS row stride (f16), rows +4 banks
#define ES 136    // evo LDS row stride (f16): 128 K-quarter cols + 8 pad
#define EMAX 50000

union F16x8 { f16x8 v; unsigned u[4]; uint2 u2[2]; };
union H2U { __half2 h; unsigned u; };
union U4H { uint4 q; __half2 h[4]; };

__device__ __forceinline__ unsigned pkrtz(float a, float b) {
  union { fp16x2_raw h; unsigned u; } c;
  c.h = __builtin_amdgcn_cvt_pkrtz(a, b);
  return c.u;
}
__device__ __forceinline__ unsigned short f2h(float x) {
  union { f16 h; unsigned short u; } c; c.h = (f16)x; return c.u;
}
#define SCHED_FENCE() __builtin_amdgcn_sched_barrier(0)

// ---- prep: gather Wq/Wv (512x512) into per-(head,ct,kst) A/B fragment-order, f16 ----
__global__ void k_prep_qv(const float* __restrict__ src, unsigned short* __restrict__ dst) {
  int i = blockIdx.x * 256 + threadIdx.x;
  int j0 = (i & 1) * 4;
  int lane = (i >> 1) & 63;
  int kst = (i >> 7) & 15;
  int ct = (i >> 11) & 3;
  int wv = (i >> 13) & 7;
  int col = wv * 64 + ct * 16 + (lane & 15);
  int row = kst * 32 + (lane >> 4) * 8 + j0;
  ushort4 o;
  o.x = f2h(src[(size_t)(row + 0) * DD + col]);
  o.y = f2h(src[(size_t)(row + 1) * DD + col]);
  o.z = f2h(src[(size_t)(row + 2) * DD + col]);
  o.w = f2h(src[(size_t)(row + 3) * DD + col]);
  *(ushort4*)&dst[(size_t)(((wv * 4 + ct) * 16 + kst) * 64 + lane) * 8 + j0] = o;
}

// ---- prep: gather Wk into qk-A-frag order (sigma slot permutation baked in) ----
__global__ void k_prep_wk(const float* __restrict__ src, unsigned short* __restrict__ dst) {
  int i = blockIdx.x * 256 + threadIdx.x;
  int j0 = (i & 1) * 4;
  int lane = (i >> 1) & 63;
  int ab = (i >> 7) & 1;
  int kst = (i >> 8) & 1;
  int ch = (i >> 9) & 15;
  int wv = (i >> 13) & 7;
  int row = ch * 32 + ab * 16 + (lane & 15);
  int cb = wv * 64 + kst * 32 + (j0 ? 16 : 0) + ((lane >> 4) & 3) * 4;
  float4 v = *(const float4*)&src[(size_t)row * DD + cb];
  ushort4 o; o.x = f2h(v.x); o.y = f2h(v.y); o.z = f2h(v.z); o.w = f2h(v.w);
  *(ushort4*)&dst[(size_t)((((wv * 16 + ch) * 2 + kst) * 2 + ab) * 64 + lane) * 8 + j0] = o;
}

// ---- prep: gather W1 (512x256) ----
__global__ void k_prep_w1(const float* __restrict__ src, unsigned short* __restrict__ dst) {
  int i = blockIdx.x * 256 + threadIdx.x;
  int j0 = (i & 1) * 4;
  int lane = (i >> 1) & 63;
  int kst = (i >> 7) & 15;
  int ct = (i >> 11) & 1;
  int wv = (i >> 12) & 7;
  int col = wv * 32 + ct * 16 + (lane & 15);
  int row = kst * 32 + (lane >> 4) * 8 + j0;
  ushort4 o;
  o.x = f2h(src[(size_t)(row + 0) * 256 + col]);
  o.y = f2h(src[(size_t)(row + 1) * 256 + col]);
  o.z = f2h(src[(size_t)(row + 2) * 256 + col]);
  o.w = f2h(src[(size_t)(row + 3) * 256 + col]);
  *(ushort4*)&dst[(size_t)(((wv * 2 + ct) * 16 + kst) * 64 + lane) * 8 + j0] = o;
}

// ---------- main: 32 entities/block, 8 waves = 8 heads, evo in K-QUARTERS, aliased LDS ----------
// r14 diagnosis: L2 weight stream (1.75MB per 16 entities) ~40% of wall. BM=32: each weight
// fragment load feeds TWO 16-entity MFMA groups -> per-entity weight traffic halved. evo in
// K-quarters (52KB) time-shares one buffer with h/Q and pooled (aliasing; barriers separate
// phases). Register quantum: arch<=64 (launch_bounds(512,4)) + ~64 AGPR <= 128 -> 4 waves/SIMD.
__global__ __launch_bounds__(512, 4) void trust_main(
    const float* __restrict__ h_i, const float* __restrict__ evo,
    const float* __restrict__ var_i, const float* __restrict__ var_j,
    const float* __restrict__ bq, const float* __restrict__ bk, const float* __restrict__ bv,
    const float* __restrict__ ld, const float* __restrict__ b1,
    const float* __restrict__ W2, const float* __restrict__ b2,
    const unsigned short* __restrict__ wqA, const unsigned short* __restrict__ wkA,
    const unsigned short* __restrict__ wvA, const unsigned short* __restrict__ w1A,
    float* __restrict__ out) {
  __shared__ unsigned short buf_s[192 * ES];  // 52224 B: h/Q (32x520) -> evo (192x136) -> pooled
  __shared__ float score_s[NH * BM * WW];     // 6144 B
  __shared__ float logit_s[BM * NH];          // 1024 B
  __shared__ float conf_s[BM];                // 128 B
  // total 59520 B -> 2 blocks/CU

  unsigned short* qh_s = buf_s;   // stride QS, 32 rows
  unsigned short* evo_s = buf_s;  // stride ES, 192 rows

  const int t = threadIdx.x;
  const int wv = t >> 6;       // wave == head
  const int l = t & 63;
  const int l16 = l & 15;
  const int lq = l >> 4;
  const int e0 = blockIdx.x * BM;
  const int row6 = e0 * 6;

  const float4* evb = (const float4*)evo;

  // ---- P0: stage h (32 rows, clamped) to qh_s; conf (32 entities, 16 lanes each) ----
  {
    const float4* h4 = (const float4*)h_i;
    #pragma unroll 4
    for (int i = 0; i < 8; ++i) {
      int idx = i * 512 + t;
      int row = idx >> 7, c4 = idx & 127;
      int ee = e0 + row; if (ee > EMAX - 1) ee = EMAX - 1;
      float4 v = h4[(size_t)ee * 128 + c4];
      uint2 o; o.x = pkrtz(v.x, v.y); o.y = pkrtz(v.z, v.w);
      *(uint2*)&qh_s[row * QS + c4 * 4] = o;
    }
    int ce = t >> 4, cs = t & 15;
    int ee = e0 + ce; if (ee > EMAX - 1) ee = EMAX - 1;
    const float4* vi4 = (const float4*)var_i + (size_t)ee * 128;
    const float4* vj4 = (const float4*)var_j + (size_t)ee * 128;
    float si = 0.f, sj = 0.f;
    #pragma unroll 4
    for (int i = 0; i < 8; ++i) {
      float4 a = vi4[i * 16 + cs]; si += a.x + a.y + a.z + a.w;
      float4 b = vj4[i * 16 + cs]; sj += b.x + b.y + b.z + b.w;
    }
    #pragma unroll
    for (int m = 1; m <= 8; m <<= 1) { si += __shfl_xor(si, m); sj += __shfl_xor(sj, m); }
    if (cs == 0) {
      float ci = 1.f / (1.f + fmaxf(sqrtf(si * (1.f / DD)), 1e-6f));
      float cj = 1.f / (1.f + fmaxf(sqrtf(sj * (1.f / DD)), 1e-6f));
      conf_s[ce] = fmaxf(0.5f * (logf(ci) + logf(cj)), -5.0f);
    }
  }
  __syncthreads();   // B1
  SCHED_FENCE();

  // ---- P1: Q for both entity groups; wq fragment loads SHARED ----
  F16x8 qfrA[2], qfrB[2];
  float qbA, qbB;
  {
    f32x4 qaccA[4] = {}, qaccB[4] = {};
    const unsigned short* wqp = wqA + (size_t)wv * 4 * 16 * 512 + l * 8;
    #pragma unroll 2
    for (int kst = 0; kst < 16; ++kst) {
      f16x8 hbA = *reinterpret_cast<const f16x8*>(&qh_s[l16 * QS + kst * 32 + lq * 8]);
      f16x8 hbB = *reinterpret_cast<const f16x8*>(&qh_s[(16 + l16) * QS + kst * 32 + lq * 8]);
      #pragma unroll
      for (int ct = 0; ct < 4; ++ct) {
        f16x8 a = *reinterpret_cast<const f16x8*>(&wqp[(ct * 16 + kst) * 512]);
        qaccA[ct] = __builtin_amdgcn_mfma_f32_16x16x32_f16(a, hbA, qaccA[ct], 0, 0, 0);
        qaccB[ct] = __builtin_amdgcn_mfma_f32_16x16x32_f16(a, hbB, qaccB[ct], 0, 0, 0);
      }
    }
    qbA = 0.f; qbB = 0.f;
    #pragma unroll
    for (int ct = 0; ct < 4; ++ct) {
      float4 bq4 = *(const float4*)&bq[wv * 64 + ct * 16 + lq * 4];
      float4 bk4 = *(const float4*)&bk[wv * 64 + ct * 16 + lq * 4];
      {
        float q0 = qaccA[ct][0] + bq4.x, q1 = qaccA[ct][1] + bq4.y;
        float q2 = qaccA[ct][2] + bq4.z, q3 = qaccA[ct][3] + bq4.w;
        qbA += q0 * bk4.x + q1 * bk4.y + q2 * bk4.z + q3 * bk4.w;
        qfrA[ct >> 1].u[(ct & 1) * 2]     = pkrtz(q0, q1);
        qfrA[ct >> 1].u[(ct & 1) * 2 + 1] = pkrtz(q2, q3);
      }
      {
        float q0 = qaccB[ct][0] + bq4.x, q1 = qaccB[ct][1] + bq4.y;
        float q2 = qaccB[ct][2] + bq4.z, q3 = qaccB[ct][3] + bq4.w;
        qbB += q0 * bk4.x + q1 * bk4.y + q2 * bk4.z + q3 * bk4.w;
        qfrB[ct >> 1].u[(ct & 1) * 2]     = pkrtz(q0, q1);
        qfrB[ct >> 1].u[(ct & 1) * 2 + 1] = pkrtz(q2, q3);
      }
    }
    qbA += __shfl_xor(qbA, 16); qbA += __shfl_xor(qbA, 32);
    qbB += __shfl_xor(qbB, 16); qbB += __shfl_xor(qbB, 32);
  }
  SCHED_FENCE();

  // ---- score: accumulate over 4 K-quarters; wk fragments shared by both groups ----
  f32x4 sA0 = {}, sA1 = {}, sA2 = {}, sA3 = {}, sA4 = {}, sA5 = {};
  f32x4 sB0 = {}, sB1 = {}, sB2 = {}, sB3 = {}, sB4 = {}, sB5 = {};
  const unsigned short* wkp = wkA + (size_t)wv * 16 * 2 * 2 * 512 + l * 8;
  const unsigned short* wvp = wvA + (size_t)wv * 4 * 16 * 512 + l * 8;

  #pragma unroll 1
  for (int q = 0; q < 4; ++q) {
    __syncthreads();   // previous buf readers done (B2/B4/B6/B8)
    #pragma unroll 4
    for (int i = 0; i < 12; ++i) {
      int idx = i * 512 + t;
      int row = idx >> 5, c4 = idx & 31;
      int gr = row6 + row; if (gr > EMAX * 6 - 1) gr = EMAX * 6 - 1;
      float4 v = evb[(size_t)gr * 128 + q * 32 + c4];
      uint2 o; o.x = pkrtz(v.x, v.y); o.y = pkrtz(v.z, v.w);
      *(uint2*)&evo_s[row * ES + c4 * 4] = o;
    }
    __syncthreads();   // B3/B5/B7/B9
    #pragma unroll 1
    for (int ci = 0; ci < 4; ++ci) {
      int ch = q * 4 + ci;
      F16x8 a00, a01, a10, a11;
      a00.v = *reinterpret_cast<const f16x8*>(&wkp[((ch * 2 + 0) * 2 + 0) * 512]);
      a01.v = *reinterpret_cast<const f16x8*>(&wkp[((ch * 2 + 0) * 2 + 1) * 512]);
      a10.v = *reinterpret_cast<const f16x8*>(&wkp[((ch * 2 + 1) * 2 + 0) * 512]);
      a11.v = *reinterpret_cast<const f16x8*>(&wkp[((ch * 2 + 1) * 2 + 1) * 512]);
      SCHED_FENCE();
      f32x4 qkA0 = {}, qkA1 = {}, qkB0 = {}, qkB1 = {};
      qkA0 = __builtin_amdgcn_mfma_f32_16x16x32_f16(a00.v, qfrA[0].v, qkA0, 0, 0, 0);
      qkA1 = __builtin_amdgcn_mfma_f32_16x16x32_f16(a01.v, qfrA[0].v, qkA1, 0, 0, 0);
      qkB0 = __builtin_amdgcn_mfma_f32_16x16x32_f16(a00.v, qfrB[0].v, qkB0, 0, 0, 0);
      qkB1 = __builtin_amdgcn_mfma_f32_16x16x32_f16(a01.v, qfrB[0].v, qkB1, 0, 0, 0);
      qkA0 = __builtin_amdgcn_mfma_f32_16x16x32_f16(a10.v, qfrA[1].v, qkA0, 0, 0, 0);
      qkA1 = __builtin_amdgcn_mfma_f32_16x16x32_f16(a11.v, qfrA[1].v, qkA1, 0, 0, 0);
      qkB0 = __builtin_amdgcn_mfma_f32_16x16x32_f16(a10.v, qfrB[1].v, qkB0, 0, 0, 0);
      qkB1 = __builtin_amdgcn_mfma_f32_16x16x32_f16(a11.v, qfrB[1].v, qkB1, 0, 0, 0);
      F16x8 afA, afB;
      afA.u[0] = pkrtz(qkA0[0], qkA0[1]); afA.u[1] = pkrtz(qkA0[2], qkA0[3]);
      afA.u[2] = pkrtz(qkA1[0], qkA1[1]); afA.u[3] = pkrtz(qkA1[2], qkA1[3]);
      afB.u[0] = pkrtz(qkB0[0], qkB0[1]); afB.u[1] = pkrtz(qkB0[2], qkB0[3]);
      afB.u[2] = pkrtz(qkB1[0], qkB1[1]); afB.u[3] = pkrtz(qkB1[2], qkB1[3]);
      int cb = ci * 32 + lq * 4;
      F16x8 b;
      b.u2[0] = *(const uint2*)&evo_s[(0 * 16 + l16) * ES + cb];
      b.u2[1] = *(const uint2*)&evo_s[(0 * 16 + l16) * ES + cb + 16];
      sA0 = __builtin_amdgcn_mfma_f32_16x16x32_f16(afA.v, b.v, sA0, 0, 0, 0);
      b.u2[0] = *(const uint2*)&evo_s[(1 * 16 + l16) * ES + cb];
      b.u2[1] = *(const uint2*)&evo_s[(1 * 16 + l16) * ES + cb + 16];
      sA1 = __builtin_amdgcn_mfma_f32_16x16x32_f16(afA.v, b.v, sA1, 0, 0, 0);
      b.u2[0] = *(const uint2*)&evo_s[(2 * 16 + l16) * ES + cb];
      b.u2[1] = *(const uint2*)&evo_s[(2 * 16 + l16) * ES + cb + 16];
      sA2 = __builtin_amdgcn_mfma_f32_16x16x32_f16(afA.v, b.v, sA2, 0, 0, 0);
      b.u2[0] = *(const uint2*)&evo_s[(3 * 16 + l16) * ES + cb];
      b.u2[1] = *(const uint2*)&evo_s[(3 * 16 + l16) * ES + cb + 16];
      sA3 = __builtin_amdgcn_mfma_f32_16x16x32_f16(afA.v, b.v, sA3, 0, 0, 0);
      b.u2[0] = *(const uint2*)&evo_s[(4 * 16 + l16) * ES + cb];
      b.u2[1] = *(const uint2*)&evo_s[(4 * 16 + l16) * ES + cb + 16];
      sA4 = __builtin_amdgcn_mfma_f32_16x16x32_f16(afA.v, b.v, sA4, 0, 0, 0);
      b.u2[0] = *(const uint2*)&evo_s[(5 * 16 + l16) * ES + cb];
      b.u2[1] = *(const uint2*)&evo_s[(5 * 16 + l16) * ES + cb + 16];
      sA5 = __builtin_amdgcn_mfma_f32_16x16x32_f16(afA.v, b.v, sA5, 0, 0, 0);
      b.u2[0] = *(const uint2*)&evo_s[(6 * 16 + l16) * ES + cb];
      b.u2[1] = *(const uint2*)&evo_s[(6 * 16 + l16) * ES + cb + 16];
      sB0 = __builtin_amdgcn_mfma_f32_16x16x32_f16(afB.v, b.v, sB0, 0, 0, 0);
      b.u2[0] = *(const uint2*)&evo_s[(7 * 16 + l16) * ES + cb];
      b.u2[1] = *(const uint2*)&evo_s[(7 * 16 + l16) * ES + cb + 16];
      sB1 = __builtin_amdgcn_mfma_f32_16x16x32_f16(afB.v, b.v, sB1, 0, 0, 0);
      b.u2[0] = *(const uint2*)&evo_s[(8 * 16 + l16) * ES + cb];
      b.u2[1] = *(const uint2*)&evo_s[(8 * 16 + l16) * ES + cb + 16];
      sB2 = __builtin_amdgcn_mfma_f32_16x16x32_f16(afB.v, b.v, sB2, 0, 0, 0);
      b.u2[0] = *(const uint2*)&evo_s[(9 * 16 + l16) * ES + cb];
      b.u2[1] = *(const uint2*)&evo_s[(9 * 16 + l16) * ES + cb + 16];
      sB3 = __builtin_amdgcn_mfma_f32_16x16x32_f16(afB.v, b.v, sB3, 0, 0, 0);
      b.u2[0] = *(const uint2*)&evo_s[(10 * 16 + l16) * ES + cb];
      b.u2[1] = *(const uint2*)&evo_s[(10 * 16 + l16) * ES + cb + 16];
      sB4 = __builtin_amdgcn_mfma_f32_16x16x32_f16(afB.v, b.v, sB4, 0, 0, 0);
      b.u2[0] = *(const uint2*)&evo_s[(11 * 16 + l16) * ES + cb];
      b.u2[1] = *(const uint2*)&evo_s[(11 * 16 + l16) * ES + cb + 16];
      sB5 = __builtin_amdgcn_mfma_f32_16x16x32_f16(afB.v, b.v, sB5, 0, 0, 0);
    }
  }
  SCHED_FENCE();

  // ---- extract S[e][w] for both groups ----
  #pragma unroll
  for (int r = 0; r < 4; ++r) {
    int e = lq * 4 + r;
    int base = l16 - 6 * e;
    { int w = base;      if (w >= 0 && w < WW) { score_s[wv * 192 + e * 6 + w] = sA0[r];
                                                score_s[wv * 192 + (16 + e) * 6 + w] = sB0[r]; } }
    { int w = base + 16; if (w >= 0 && w < WW) { score_s[wv * 192 + e * 6 + w] = sA1[r];
                                                score_s[wv * 192 + (16 + e) * 6 + w] = sB1[r]; } }
    { int w = base + 32; if (w >= 0 && w < WW) { score_s[wv * 192 + e * 6 + w] = sA2[r];
                                                score_s[wv * 192 + (16 + e) * 6 + w] = sB2[r]; } }
    { int w = base + 48; if (w >= 0 && w < WW) { score_s[wv * 192 + e * 6 + w] = sA3[r];
                                                score_s[wv * 192 + (16 + e) * 6 + w] = sB3[r]; } }
    { int w = base + 64; if (w >= 0 && w < WW) { score_s[wv * 192 + e * 6 + w] = sA4[r];
                                                score_s[wv * 192 + (16 + e) * 6 + w] = sB4[r]; } }
    { int w = base + 80; if (w >= 0 && w < WW) { score_s[wv * 192 + e * 6 + w] = sA5[r];
                                                score_s[wv * 192 + (16 + e) * 6 + w] = sB5[r]; } }
  }
  // decay bias (computed here to shorten live range through score phase)
  float biasw[WW];
  {
    float rd = expf(ld[0]);
    float dsum = 0.f;
    #pragma unroll
    for (int w6 = 0; w6 < WW; ++w6) { biasw[w6] = expf(rd * (float)w6); dsum += biasw[w6]; }
    float dinv = 1.f / dsum;
    #pragma unroll
    for (int w6 = 0; w6 < WW; ++w6) biasw[w6] *= dinv;
  }
  // softmax, both groups (same-wave LDS ordering; l16==0 lanes write attn back)
  #pragma unroll
  for (int r = 0; r < 4; ++r) {
    int e = lq * 4 + r;
    float qbvA = __shfl(qbA, e);
    float qbvB = __shfl(qbB, e);
    float scA[WW], scB[WW]; float mxA = -1e30f, mxB = -1e30f;
    #pragma unroll
    for (int w6 = 0; w6 < WW; ++w6) {
      scA[w6] = 0.125f * (score_s[wv * 192 + e * 6 + w6] + qbvA) + biasw[w6];
      scB[w6] = 0.125f * (score_s[wv * 192 + (16 + e) * 6 + w6] + qbvB) + biasw[w6];
      mxA = fmaxf(mxA, scA[w6]); mxB = fmaxf(mxB, scB[w6]);
    }
    float ssA = 0.f, ssB = 0.f;
    #pragma unroll
    for (int w6 = 0; w6 < WW; ++w6) {
      scA[w6] = expf(scA[w6] - mxA); ssA += scA[w6];
      scB[w6] = expf(scB[w6] - mxB); ssB += scB[w6];
    }
    float siA = 1.f / ssA, siB = 1.f / ssB;
    if (l16 == 0) {
      #pragma unroll
      for (int w6 = 0; w6 < WW; ++w6) {
        score_s[wv * 192 + e * 6 + w6] = scA[w6] * siA;
        score_s[wv * 192 + (16 + e) * 6 + w6] = scB[w6] * siB;
      }
    }
  }
  SCHED_FENCE();

  // ---- agg + pooled over K-quarters in reverse (q3 resident); wv fragments shared ----
  f32x4 paccA[4] = {}, paccB[4] = {};
  {
    __half2 aw2A[WW], aw2B[WW];
    #pragma unroll
    for (int w6 = 0; w6 < WW; ++w6) {
      float vA = score_s[wv * 192 + l16 * 6 + w6];
      float vB = score_s[wv * 192 + (16 + l16) * 6 + w6];
      H2U a; a.u = pkrtz(vA, vA); aw2A[w6] = a.h;
      H2U c; c.u = pkrtz(vB, vB); aw2B[w6] = c.h;
    }
    const int arowA = l16 * 6, arowB = 96 + l16 * 6;
    #pragma unroll 1
    for (int q = 3; q >= 0; --q) {
      if (q != 3) {
        __syncthreads();   // all waves done with previous quarter agg reads
        #pragma unroll 4
        for (int i = 0; i < 12; ++i) {
          int idx = i * 512 + t;
          int row = idx >> 5, c4 = idx & 31;
          int gr = row6 + row; if (gr > EMAX * 6 - 1) gr = EMAX * 6 - 1;
          float4 v = evb[(size_t)gr * 128 + q * 32 + c4];
          uint2 o; o.x = pkrtz(v.x, v.y); o.y = pkrtz(v.z, v.w);
          *(uint2*)&evo_s[row * ES + c4 * 4] = o;
        }
        __syncthreads();
      }
      #pragma unroll 1
      for (int ci = 0; ci < 4; ++ci) {
        int ch = q * 4 + ci;
        F16x8 v0, v1, v2, v3;
        v0.v = *reinterpret_cast<const f16x8*>(&wvp[(0 * 16 + ch) * 512]);
        v1.v = *reinterpret_cast<const f16x8*>(&wvp[(1 * 16 + ch) * 512]);
        v2.v = *reinterpret_cast<const f16x8*>(&wvp[(2 * 16 + ch) * 512]);
        v3.v = *reinterpret_cast<const f16x8*>(&wvp[(3 * 16 + ch) * 512]);
        SCHED_FENCE();
        H2U z; z.u = 0;
        __half2 aA0 = z.h, aA1 = z.h, aA2 = z.h, aA3 = z.h;
        __half2 aB0 = z.h, aB1 = z.h, aB2 = z.h, aB3 = z.h;
        #pragma unroll
        for (int w6 = 0; w6 < WW; ++w6) {
          U4H vv; vv.q = *(const uint4*)&evo_s[(arowA + w6) * ES + ci * 32 + lq * 8];
          aA0 = __hfma2(vv.h[0], aw2A[w6], aA0);
          aA1 = __hfma2(vv.h[1], aw2A[w6], aA1);
          aA2 = __hfma2(vv.h[2], aw2A[w6], aA2);
          aA3 = __hfma2(vv.h[3], aw2A[w6], aA3);
        }
        #pragma unroll
        for (int w6 = 0; w6 < WW; ++w6) {
          U4H vv; vv.q = *(const uint4*)&evo_s[(arowB + w6) * ES + ci * 32 + lq * 8];
          aB0 = __hfma2(vv.h[0], aw2B[w6], aB0);
          aB1 = __hfma2(vv.h[1], aw2B[w6], aB1);
          aB2 = __hfma2(vv.h[2], aw2B[w6], aB2);
          aB3 = __hfma2(vv.h[3], aw2B[w6], aB3);
        }
        F16x8 afA, afB;
        { H2U c; c.h = aA0; afA.u[0] = c.u; c.h = aA1; afA.u[1] = c.u;
          c.h = aA2; afA.u[2] = c.u; c.h = aA3; afA.u[3] = c.u;
          c.h = aB0; afB.u[0] = c.u; c.h = aB1; afB.u[1] = c.u;
          c.h = aB2; afB.u[2] = c.u; c.h = aB3; afB.u[3] = c.u; }
        paccA[0] = __builtin_amdgcn_mfma_f32_16x16x32_f16(afA.v, v0.v, paccA[0], 0, 0, 0);
        paccB[0] = __builtin_amdgcn_mfma_f32_16x16x32_f16(afB.v, v0.v, paccB[0], 0, 0, 0);
        paccA[1] = __builtin_amdgcn_mfma_f32_16x16x32_f16(afA.v, v1.v, paccA[1], 0, 0, 0);
        paccB[1] = __builtin_amdgcn_mfma_f32_16x16x32_f16(afB.v, v1.v, paccB[1], 0, 0, 0);
        paccA[2] = __builtin_amdgcn_mfma_f32_16x16x32_f16(afA.v, v2.v, paccA[2], 0, 0, 0);
        paccB[2] = __builtin_amdgcn_mfma_f32_16x16x32_f16(afB.v, v2.v, paccB[2], 0, 0, 0);
        paccA[3] = __builtin_amdgcn_mfma_f32_16x16x32_f16(afA.v, v3.v, paccA[3], 0, 0, 0);
        paccB[3] = __builtin_amdgcn_mfma_f32_16x16x32_f16(afB.v, v3.v, paccB[3], 0, 0, 0);
      }
    }
  }

  __syncthreads();   // all agg evo reads done before pooled overwrites buf
  #pragma unroll
  for (int ct = 0; ct < 4; ++ct) {
    int col = wv * 64 + ct * 16 + l16;
    float bvv = bv[col];
    #pragma unroll
    for (int r = 0; r < 4; ++r) {
      qh_s[(lq * 4 + r) * QS + col] = f2h(paccA[ct][r] + bvv);
      qh_s[(16 + lq * 4 + r) * QS + col] = f2h(paccB[ct][r] + bvv);
    }
  }
  __syncthreads();

  // ---- P6: hmid = gelu(pooled @ W1 + b1); logit partials, both groups ----
  {
    f32x4 haccA[2] = {}, haccB[2] = {};
    const unsigned short* w1p = w1A + (size_t)wv * 2 * 16 * 512 + l * 8;
    #pragma unroll 2
    for (int kst = 0; kst < 16; ++kst) {
      f16x8 aA = *reinterpret_cast<const f16x8*>(&qh_s[l16 * QS + kst * 32 + lq * 8]);
      f16x8 aB = *reinterpret_cast<const f16x8*>(&qh_s[(16 + l16) * QS + kst * 32 + lq * 8]);
      #pragma unroll
      for (int ct = 0; ct < 2; ++ct) {
        f16x8 b = *reinterpret_cast<const f16x8*>(&w1p[(ct * 16 + kst) * 512]);
        haccA[ct] = __builtin_amdgcn_mfma_f32_16x16x32_f16(aA, b, haccA[ct], 0, 0, 0);
        haccB[ct] = __builtin_amdgcn_mfma_f32_16x16x32_f16(aB, b, haccB[ct], 0, 0, 0);
      }
    }
    float lgA[4] = {0.f, 0.f, 0.f, 0.f}, lgB[4] = {0.f, 0.f, 0.f, 0.f};
    #pragma unroll
    for (int ct = 0; ct < 2; ++ct) {
      int m = wv * 32 + ct * 16 + l16;
      float b1v = b1[m], w2v = W2[m];
      #pragma unroll
      for (int r = 0; r < 4; ++r) {
        float xA = haccA[ct][r] + b1v;
        lgA[r] += 0.5f * xA * (1.f + erff(xA * 0.70710678118f)) * w2v;
        float xB = haccB[ct][r] + b1v;
        lgB[r] += 0.5f * xB * (1.f + erff(xB * 0.70710678118f)) * w2v;
      }
    }
    #pragma unroll
    for (int r = 0; r < 4; ++r) {
      #pragma unroll
      for (int m = 1; m <= 8; m <<= 1) {
        lgA[r] += __shfl_xor(lgA[r], m);
        lgB[r] += __shfl_xor(lgB[r], m);
      }
    }
    if (l16 == 0) {
      #pragma unroll
      for (int r = 0; r < 4; ++r) {
        logit_s[(lq * 4 + r) * NH + wv] = lgA[r];
        logit_s[(16 + lq * 4 + r) * NH + wv] = lgB[r];
      }
    }
  }
  __syncthreads();

  // ---- P7: combine + sigmoid (guarded for tail block) ----
  if (t < BM) {
    int ee = e0 + t;
    if (ee < EMAX) {
      float s = 0.f;
      #pragma unroll
      for (int w8 = 0; w8 < NH; ++w8) s += logit_s[t * NH + w8];
      s += b2[0] + conf_s[t];
      out[ee] = 1.f / (1.f + expf(-s));
    }
  }
}

extern "C" void kernel_launch(void* const* d_in, const int* in_sizes, int n_in,
                              void* d_out, int out_size, void* d_ws, size_t ws_size,
                              hipStream_t stream) {
  (void)in_sizes; (void)n_in; (void)out_size; (void)ws_size;
  const float* h_i = (const float*)d_in[0];
  const float* evo = (const float*)d_in[1];
  const float* vi  = (const float*)d_in[2];
  const float* vj  = (const float*)d_in[3];
  const float* Wq  = (const float*)d_in[4];
  const float* bq  = (const float*)d_in[5];
  const float* Wk  = (const float*)d_in[6];
  const float* bk  = (const float*)d_in[7];
  const float* Wv  = (const float*)d_in[8];
  const float* bv  = (const float*)d_in[9];
  const float* ld  = (const float*)d_in[10];
  const float* W1  = (const float*)d_in[11];
  const float* b1  = (const float*)d_in[12];
  const float* W2  = (const float*)d_in[13];
  const float* b2  = (const float*)d_in[14];
  float* out = (float*)d_out;

  unsigned short* ws  = (unsigned short*)d_ws;
  unsigned short* wqA = ws;            // 512KB f16, Wq fragment-order
  unsigned short* wkA = ws + 262144;   // 512KB f16, Wk qk-A-frag order
  unsigned short* wvA = ws + 524288;   // 512KB f16, Wv B-frag order
  unsigned short* w1A = ws + 786432;   // 256KB f16, W1 B-frag order

  k_prep_qv<<<256, 256, 0, stream>>>(Wq, wqA);
  k_prep_wk<<<256, 256, 0, stream>>>(Wk, wkA);
  k_prep_qv<<<256, 256, 0, stream>>>(Wv, wvA);
  k_prep_w1<<<128, 256, 0, stream>>>(W1, w1A);
  trust_main<<<1563, 512, 0, stream>>>(h_i, evo, vi, vj, bq, bk, bv, ld, b1, W2, b2,
                                       wqA, wkA, wvA, w1A, out);
}